// Round 1
// baseline (6360.624 us; speedup 1.0000x reference)
//
#include <hip/hip_runtime.h>

#define NPTS 2048
#define BATCH 8
#define KNN 20

__device__ __forceinline__ float leaky(float y) { return fmaxf(y, 0.2f * y); }

// ---------------- prep: Wp[2O][C] = [a*W1 ; a*(W2-W1)] ----------------
__global__ void prep_w_kernel(const float* __restrict__ W, const float* __restrict__ g,
                              float* __restrict__ Wp, int O, int C) {
  int t = blockIdx.x * 256 + threadIdx.x;
  if (t >= 2 * O * C) return;
  int row = t / C, c = t - row * C;
  float inv = rsqrtf(1.0f + 1e-5f);
  if (row < O) {
    Wp[t] = g[row] * inv * W[row * 2 * C + c];
  } else {
    int o = row - O;
    Wp[t] = g[o] * inv * (W[o * 2 * C + C + c] - W[o * 2 * C + c]);
  }
}

__global__ void prep_mlpw_kernel(const float* __restrict__ W, const float* __restrict__ g,
                                 float* __restrict__ Wm) {
  int t = blockIdx.x * 256 + threadIdx.x;
  if (t >= 1024 * 512) return;
  int o = t >> 9;
  Wm[t] = g[o] * rsqrtf(1.0f + 1e-5f) * W[t];
}

// ---------------- xx[b][m] = sum_c x[c][m]^2 ----------------
__global__ void xx_kernel(const float* __restrict__ x, float* __restrict__ xx,
                          int C, long bstride) {
  int b = blockIdx.y;
  int m = blockIdx.x * 256 + threadIdx.x;
  const float* xb = x + (long)b * bstride;
  float s = 0.f;
  for (int c = 0; c < C; ++c) { float v = xb[c * NPTS + m]; s += v * v; }
  xx[b * NPTS + m] = s;
}

// ---------------- fused knn: tiled x^T x gemm + streaming top-20 ----------------
__global__ __launch_bounds__(256) void knn_kernel(const float* __restrict__ x,
                                                  const float* __restrict__ xx,
                                                  int* __restrict__ idxout,
                                                  int C, long bstride) {
  __shared__ float xnT[128 * 64];   // [c][64 rows]
  __shared__ float xmT[32 * 65];    // [kc][64 m] padded
  __shared__ float d2t[64 * 65];    // [row][64 m] padded
  __shared__ float listd[64 * 21];
  __shared__ int   listi[64 * 21];
  __shared__ float xxnS[64];

  int tid = threadIdx.x;
  int b = blockIdx.y;
  int n0 = blockIdx.x * 64;
  const float* xb = x + (long)b * bstride;
  const float* xxb = xx + b * NPTS;

  for (int i = tid; i < C * 64; i += 256) {
    int c = i >> 6, j = i & 63;
    xnT[c * 64 + j] = xb[c * NPTS + n0 + j];
  }
  if (tid < 64) {
    xxnS[tid] = xxb[n0 + tid];
    for (int k = 0; k < KNN; ++k) { listd[tid * 21 + k] = 1e30f; listi[tid * 21 + k] = 0; }
  }
  int ti = tid >> 4, tj = tid & 15;

  for (int mt = 0; mt < NPTS / 64; ++mt) {
    int m0 = mt * 64;
    float acc[4][4];
    #pragma unroll
    for (int r = 0; r < 4; ++r)
      #pragma unroll
      for (int m = 0; m < 4; ++m) acc[r][m] = 0.f;

    for (int k0 = 0; k0 < C; k0 += 32) {
      int kcnt = min(32, C - k0);
      __syncthreads();
      for (int i = tid; i < kcnt * 64; i += 256) {
        int kc = i >> 6, j = i & 63;
        xmT[kc * 65 + j] = xb[(k0 + kc) * NPTS + m0 + j];
      }
      __syncthreads();
      for (int kc = 0; kc < kcnt; ++kc) {
        float av[4], bv[4];
        #pragma unroll
        for (int r = 0; r < 4; ++r) av[r] = xnT[(k0 + kc) * 64 + ti * 4 + r];
        #pragma unroll
        for (int m = 0; m < 4; ++m) bv[m] = xmT[kc * 65 + tj * 4 + m];
        #pragma unroll
        for (int r = 0; r < 4; ++r)
          #pragma unroll
          for (int m = 0; m < 4; ++m) acc[r][m] += av[r] * bv[m];
      }
    }
    float xxm[4];
    #pragma unroll
    for (int m = 0; m < 4; ++m) xxm[m] = xxb[m0 + tj * 4 + m];
    #pragma unroll
    for (int r = 0; r < 4; ++r) {
      float xv = xxnS[ti * 4 + r];
      #pragma unroll
      for (int m = 0; m < 4; ++m)
        d2t[(ti * 4 + r) * 65 + tj * 4 + m] = xv + xxm[m] - 2.f * acc[r][m];
    }
    __syncthreads();
    if (tid < 64) {
      int base = tid * 21;
      for (int i2 = 0; i2 < 64; ++i2) {
        float val = d2t[tid * 65 + i2];
        if (val < listd[base + 19]) {
          int pos = 19;
          while (pos > 0 && listd[base + pos - 1] > val) {
            listd[base + pos] = listd[base + pos - 1];
            listi[base + pos] = listi[base + pos - 1];
            --pos;
          }
          listd[base + pos] = val;
          listi[base + pos] = m0 + i2;
        }
      }
    }
    __syncthreads();
  }
  if (tid < 64) {
    int* op = idxout + (b * NPTS + n0 + tid) * KNN;
    for (int k = 0; k < KNN; ++k) op[k] = listi[tid * 21 + k];
  }
}

// ---------------- vsus[b][n][p] = sum_c Wp[p][c] * x[c][n] ----------------
__global__ __launch_bounds__(256) void gemm_vsus_kernel(const float* __restrict__ x,
                                                        const float* __restrict__ Wp,
                                                        float* __restrict__ out,
                                                        int C, int P2, long bstride) {
  __shared__ float xs[32 * 65];
  __shared__ float wsd[32 * 65];
  int tid = threadIdx.x;
  int b = blockIdx.z;
  int n0 = blockIdx.x * 64;
  int p0 = blockIdx.y * 64;
  const float* xb = x + (long)b * bstride;
  float acc[4][4];
  #pragma unroll
  for (int r = 0; r < 4; ++r)
    #pragma unroll
    for (int m = 0; m < 4; ++m) acc[r][m] = 0.f;
  int ti = tid >> 4, tj = tid & 15;

  for (int k0 = 0; k0 < C; k0 += 32) {
    int kcnt = min(32, C - k0);
    __syncthreads();
    for (int i = tid; i < kcnt * 64; i += 256) {
      int kc = i >> 6, j = i & 63;
      xs[kc * 65 + j] = xb[(k0 + kc) * NPTS + n0 + j];
    }
    for (int i = tid; i < kcnt * 64; i += 256) {
      int kc = i % kcnt, p = i / kcnt;
      wsd[kc * 65 + p] = Wp[(p0 + p) * C + k0 + kc];
    }
    __syncthreads();
    for (int kc = 0; kc < kcnt; ++kc) {
      float av[4], bv[4];
      #pragma unroll
      for (int r = 0; r < 4; ++r) av[r] = xs[kc * 65 + ti * 4 + r];
      #pragma unroll
      for (int m = 0; m < 4; ++m) bv[m] = wsd[kc * 65 + tj * 4 + m];
      #pragma unroll
      for (int r = 0; r < 4; ++r)
        #pragma unroll
        for (int m = 0; m < 4; ++m) acc[r][m] += av[r] * bv[m];
    }
  }
  #pragma unroll
  for (int r = 0; r < 4; ++r) {
    int n = n0 + ti * 4 + r;
    float4 v = make_float4(acc[r][0], acc[r][1], acc[r][2], acc[r][3]);
    *reinterpret_cast<float4*>(out + (long)(b * NPTS + n) * P2 + p0 + tj * 4) = v;
  }
}

// ---------------- gather + max_k + leaky -> xcat channel block ----------------
__global__ __launch_bounds__(256) void gather_max_kernel(const float* __restrict__ vsus,
                                                         const int* __restrict__ idxin,
                                                         const float* __restrict__ bias,
                                                         float* __restrict__ xcat,
                                                         int O, int cho) {
  __shared__ int idxs[32 * KNN];
  __shared__ float ot[256 * 33];
  int tid = threadIdx.x;
  int b = blockIdx.y;
  int n0 = blockIdx.x * 32;
  int P2 = 2 * O;
  for (int i = tid; i < 32 * KNN; i += 256) idxs[i] = idxin[(b * NPTS + n0) * KNN + i];
  __syncthreads();
  int G = 256 / O;
  int o = tid % O;
  int ns = tid / O;
  float bo = bias[o];
  const float* vb = vsus + (long)b * NPTS * P2;
  for (int step = 0; step < 32 / G; ++step) {
    int nn = step * G + ns;
    float mx = -1e30f;
    for (int k = 0; k < KNN; ++k) {
      int j = idxs[nn * KNN + k];
      mx = fmaxf(mx, vb[j * P2 + o]);
    }
    float us = vb[(n0 + nn) * P2 + O + o] + bo;
    ot[o * 33 + nn] = leaky(mx + us);
  }
  __syncthreads();
  float* ob = xcat + ((long)b * 512 + cho) * NPTS + n0;
  for (int i = tid; i < O * 32; i += 256) {
    int oo = i >> 5, nn = i & 31;
    ob[oo * NPTS + nn] = ot[oo * 33 + nn];
  }
}

// ---------------- mlp gemm fused with partial max/sum over n ----------------
__global__ __launch_bounds__(256) void mlp_kernel(const float* __restrict__ xcat,
                                                  const float* __restrict__ Wm,
                                                  const float* __restrict__ bvec,
                                                  float* __restrict__ pbuf) {
  __shared__ float xs[32 * 65];
  __shared__ float wsd[32 * 65];
  __shared__ float red[2 * 64 * 17];
  int tid = threadIdx.x;
  int b = blockIdx.z;
  int ot = blockIdx.y;   // 16 tiles of 64 o
  int nt = blockIdx.x;   // 4 tiles of 512 n
  int o0 = ot * 64;
  const float* xb = xcat + (long)b * 512 * NPTS;
  int ti = tid >> 4, tj = tid & 15;
  float bb[4];
  #pragma unroll
  for (int m = 0; m < 4; ++m) bb[m] = bvec[o0 + tj * 4 + m];
  float rmax[4] = {-1e30f, -1e30f, -1e30f, -1e30f};
  float rsum[4] = {0.f, 0.f, 0.f, 0.f};

  for (int nsub = 0; nsub < 8; ++nsub) {
    int n0 = nt * 512 + nsub * 64;
    float acc[4][4];
    #pragma unroll
    for (int r = 0; r < 4; ++r)
      #pragma unroll
      for (int m = 0; m < 4; ++m) acc[r][m] = 0.f;
    for (int k0 = 0; k0 < 512; k0 += 32) {
      __syncthreads();
      for (int i = tid; i < 32 * 64; i += 256) {
        int kc = i >> 6, j = i & 63;
        xs[kc * 65 + j] = xb[(k0 + kc) * NPTS + n0 + j];
      }
      for (int i = tid; i < 32 * 64; i += 256) {
        int kc = i & 31, p = i >> 5;
        wsd[kc * 65 + p] = Wm[(o0 + p) * 512 + k0 + kc];
      }
      __syncthreads();
      for (int kc = 0; kc < 32; ++kc) {
        float av[4], bv[4];
        #pragma unroll
        for (int r = 0; r < 4; ++r) av[r] = xs[kc * 65 + ti * 4 + r];
        #pragma unroll
        for (int m = 0; m < 4; ++m) bv[m] = wsd[kc * 65 + tj * 4 + m];
        #pragma unroll
        for (int r = 0; r < 4; ++r)
          #pragma unroll
          for (int m = 0; m < 4; ++m) acc[r][m] += av[r] * bv[m];
      }
    }
    #pragma unroll
    for (int r = 0; r < 4; ++r)
      #pragma unroll
      for (int m = 0; m < 4; ++m) {
        float y = leaky(acc[r][m] + bb[m]);
        rmax[m] = fmaxf(rmax[m], y);
        rsum[m] += y;
      }
  }
  __syncthreads();
  #pragma unroll
  for (int m = 0; m < 4; ++m) {
    red[(tj * 4 + m) * 17 + ti] = rmax[m];
    red[64 * 17 + (tj * 4 + m) * 17 + ti] = rsum[m];
  }
  __syncthreads();
  if (tid < 64) {
    float mx = -1e30f, s = 0.f;
    for (int i = 0; i < 16; ++i) {
      mx = fmaxf(mx, red[tid * 17 + i]);
      s += red[64 * 17 + tid * 17 + i];
    }
    float* pb = pbuf + (((b * 16 + ot) * 4 + nt) * 2) * 64;
    pb[tid] = mx;
    pb[64 + tid] = s;
  }
}

__global__ void mlp_reduce_kernel(const float* __restrict__ pbuf, float* __restrict__ feat) {
  int t = blockIdx.x * 256 + threadIdx.x;   // 8192
  int b = t >> 10, o = t & 1023;
  int ot = o >> 6, oo = o & 63;
  float mx = -1e30f, s = 0.f;
  for (int nt = 0; nt < 4; ++nt) {
    const float* pb = pbuf + (((b * 16 + ot) * 4 + nt) * 2) * 64;
    mx = fmaxf(mx, pb[oo]);
    s += pb[64 + oo];
  }
  feat[b * 2048 + o] = mx;
  feat[b * 2048 + 1024 + o] = s * (1.f / 2048.f);
}

// ---------------- fc layers: one wave per output ----------------
__global__ void fc_kernel(const float* __restrict__ X, const float* __restrict__ W,
                          const float* __restrict__ bias, const float* __restrict__ g,
                          const float* __restrict__ bb, float* __restrict__ out,
                          int B, int O, int Kdim, int hasAct) {
  int gt = blockIdx.x * 256 + threadIdx.x;
  int wid = gt >> 6;
  int lane = threadIdx.x & 63;
  if (wid >= B * O) return;
  int b = wid / O, o = wid - b * O;
  const float* xr = X + (long)b * Kdim;
  const float* wr = W + (long)o * Kdim;
  float acc = 0.f;
  for (int c = lane; c < Kdim; c += 64) acc += xr[c] * wr[c];
  for (int off = 32; off; off >>= 1) acc += __shfl_down(acc, off);
  if (lane == 0) {
    float h = acc + bias[o];
    if (hasAct) {
      float a = g[o] * rsqrtf(1.0f + 1e-5f);
      h = a * h + bb[o];
      h = fmaxf(h, 0.2f * h);
    }
    out[b * O + o] = h;
  }
}

// ---------------- launch ----------------
extern "C" void kernel_launch(void* const* d_in, const int* in_sizes, int n_in,
                              void* d_out, int out_size, void* d_ws, size_t ws_size,
                              hipStream_t stream) {
  const float* points = (const float*)d_in[0];
  char* ws = (char*)d_ws;

  const size_t XCAT = 0;                         // [8][512][2048] f
  const size_t VSUS = 33554432;                  // [8][2048][512] f
  const size_t IDXB = 67108864;                  // [8][2048][20] i
  const size_t XXB  = 68419584;                  // [8][2048] f
  const size_t WP   = 68485120;                  // [512][128] f
  const size_t WMLP = 68747264;                  // [1024][512] f
  const size_t PBUF = 70844416;                  // 65536 f
  const size_t FEAT = 71106560;                  // [8][2048] f
  const size_t H1   = 71172096;                  // [8][512] f
  const size_t H2   = 71188480;                  // [8][256] f

  float* xcat = (float*)(ws + XCAT);
  float* vsus = (float*)(ws + VSUS);
  int*   idxb = (int*)(ws + IDXB);
  float* xxb  = (float*)(ws + XXB);
  float* wp   = (float*)(ws + WP);
  float* wmlp = (float*)(ws + WMLP);
  float* pbuf = (float*)(ws + PBUF);
  float* feat = (float*)(ws + FEAT);
  float* h1   = (float*)(ws + H1);
  float* h2   = (float*)(ws + H2);

  struct Layer { const float* x; long bstride; int C, O, cho, wi, gi, bi; };
  Layer layers[4] = {
    { points,              (long)3 * NPTS,   3,   64, 0,   1, 2, 3 },
    { xcat,                (long)512 * NPTS, 64,  64, 64,  4, 5, 6 },
    { xcat + 64 * NPTS,    (long)512 * NPTS, 64,  128, 128, 7, 8, 9 },
    { xcat + 128 * NPTS,   (long)512 * NPTS, 128, 256, 256, 10, 11, 12 },
  };

  for (int L = 0; L < 4; ++L) {
    Layer& ly = layers[L];
    int P2 = 2 * ly.O;
    const float* W = (const float*)d_in[ly.wi];
    const float* g = (const float*)d_in[ly.gi];
    const float* bv = (const float*)d_in[ly.bi];

    int wtot = 2 * ly.O * ly.C;
    prep_w_kernel<<<(wtot + 255) / 256, 256, 0, stream>>>(W, g, wp, ly.O, ly.C);
    xx_kernel<<<dim3(NPTS / 256, BATCH), 256, 0, stream>>>(ly.x, xxb, ly.C, ly.bstride);
    knn_kernel<<<dim3(NPTS / 64, BATCH), 256, 0, stream>>>(ly.x, xxb, idxb, ly.C, ly.bstride);
    gemm_vsus_kernel<<<dim3(NPTS / 64, P2 / 64, BATCH), 256, 0, stream>>>(
        ly.x, wp, vsus, ly.C, P2, ly.bstride);
    gather_max_kernel<<<dim3(NPTS / 32, BATCH), 256, 0, stream>>>(
        vsus, idxb, bv, xcat, ly.O, ly.cho);
  }

  prep_mlpw_kernel<<<(1024 * 512 + 255) / 256, 256, 0, stream>>>(
      (const float*)d_in[13], (const float*)d_in[14], wmlp);
  mlp_kernel<<<dim3(4, 16, BATCH), 256, 0, stream>>>(
      xcat, wmlp, (const float*)d_in[15], pbuf);
  mlp_reduce_kernel<<<32, 256, 0, stream>>>(pbuf, feat);

  fc_kernel<<<(BATCH * 512 * 64) / 256, 256, 0, stream>>>(
      feat, (const float*)d_in[16], (const float*)d_in[17],
      (const float*)d_in[18], (const float*)d_in[19], h1, BATCH, 512, 2048, 1);
  fc_kernel<<<(BATCH * 256 * 64) / 256, 256, 0, stream>>>(
      h1, (const float*)d_in[20], (const float*)d_in[21],
      (const float*)d_in[22], (const float*)d_in[23], h2, BATCH, 256, 512, 1);
  fc_kernel<<<(BATCH * 40 * 64) / 256, 256, 0, stream>>>(
      h2, (const float*)d_in[24], (const float*)d_in[25],
      nullptr, nullptr, (float*)d_out, BATCH, 40, 256, 0);
}

// Round 2
// 3515.682 us; speedup vs baseline: 1.8092x; 1.8092x over previous
//
#include <hip/hip_runtime.h>

#define NPTS 2048
#define BATCH 8
#define KNN 20

__device__ __forceinline__ float leaky(float y) { return fmaxf(y, 0.2f * y); }

// ---------------- prep: Wp[2O][C] = [a*W1 ; a*(W2-W1)] ----------------
__global__ void prep_w_kernel(const float* __restrict__ W, const float* __restrict__ g,
                              float* __restrict__ Wp, int O, int C) {
  int t = blockIdx.x * 256 + threadIdx.x;
  if (t >= 2 * O * C) return;
  int row = t / C, c = t - row * C;
  float inv = rsqrtf(1.0f + 1e-5f);
  if (row < O) {
    Wp[t] = g[row] * inv * W[row * 2 * C + c];
  } else {
    int o = row - O;
    Wp[t] = g[o] * inv * (W[o * 2 * C + C + c] - W[o * 2 * C + c]);
  }
}

__global__ void prep_mlpw_kernel(const float* __restrict__ W, const float* __restrict__ g,
                                 float* __restrict__ Wm) {
  int t = blockIdx.x * 256 + threadIdx.x;
  if (t >= 1024 * 512) return;
  int o = t >> 9;
  Wm[t] = g[o] * rsqrtf(1.0f + 1e-5f) * W[t];
}

// ---------------- xx[b][m] = sum_c x[c][m]^2 ----------------
__global__ void xx_kernel(const float* __restrict__ x, float* __restrict__ xx,
                          int C, long bstride) {
  int b = blockIdx.y;
  int m = blockIdx.x * 256 + threadIdx.x;
  const float* xb = x + (long)b * bstride;
  float s = 0.f;
  for (int c = 0; c < C; ++c) { float v = xb[c * NPTS + m]; s += v * v; }
  xx[b * NPTS + m] = s;
}

// ---------------- fused knn: tiled x^T x gemm + register top-20, all lanes ----------------
template <int C>
__global__ __launch_bounds__(256) void knn_kernel(const float* __restrict__ x,
                                                  const float* __restrict__ xx,
                                                  int* __restrict__ idxout,
                                                  long bstride) {
  constexpr int XN = C * 64;
  constexpr int XM = 32 * 65;
  constexpr int D2 = 64 * 65;
  constexpr int MAIN = XN + XM + D2 + 64;
  constexpr int MRG = 2 * 4 * 64 * 21;   // dist + idx lists, stride 21
  constexpr int SM = MAIN > MRG ? MAIN : MRG;
  __shared__ float smem[SM];
  float* xnT = smem;
  float* xmT = smem + XN;
  float* d2t = smem + XN + XM;
  float* xxnS = smem + XN + XM + D2;
  float* mrgD = smem;                       // aliased after main loop
  int*   mrgI = (int*)(smem + 4 * 64 * 21);

  int tid = threadIdx.x;
  int b = blockIdx.y;
  int n0 = blockIdx.x * 64;
  const float* xb = x + (long)b * bstride;
  const float* xxb = xx + b * NPTS;

  for (int i = tid; i < C * 64; i += 256) {
    int c = i >> 6, j = i & 63;
    xnT[c * 64 + j] = xb[c * NPTS + n0 + j];
  }
  if (tid < 64) xxnS[tid] = xxb[n0 + tid];

  // per-thread top-20 in registers (thread owns row = tid&63, m-partition = tid>>6)
  float ld[20]; int li[20];
  #pragma unroll
  for (int k = 0; k < 20; ++k) { ld[k] = 1e30f; li[k] = 0x7fffffff; }

  int ti = tid >> 4, tj = tid & 15;
  int row = tid & 63, part = tid >> 6;

  for (int mt = 0; mt < NPTS / 64; ++mt) {
    int m0 = mt * 64;
    float acc[4][4];
    #pragma unroll
    for (int r = 0; r < 4; ++r)
      #pragma unroll
      for (int m = 0; m < 4; ++m) acc[r][m] = 0.f;

    for (int k0 = 0; k0 < C; k0 += 32) {
      int kcnt = (C - k0) < 32 ? (C - k0) : 32;
      __syncthreads();
      for (int i = tid; i < kcnt * 64; i += 256) {
        int kc = i >> 6, j = i & 63;
        xmT[kc * 65 + j] = xb[(k0 + kc) * NPTS + m0 + j];
      }
      __syncthreads();
      for (int kc = 0; kc < kcnt; ++kc) {
        float av[4], bv[4];
        #pragma unroll
        for (int r = 0; r < 4; ++r) av[r] = xnT[(k0 + kc) * 64 + ti * 4 + r];
        #pragma unroll
        for (int m = 0; m < 4; ++m) bv[m] = xmT[kc * 65 + tj * 4 + m];
        #pragma unroll
        for (int r = 0; r < 4; ++r)
          #pragma unroll
          for (int m = 0; m < 4; ++m) acc[r][m] += av[r] * bv[m];
      }
    }
    float xxm[4];
    #pragma unroll
    for (int m = 0; m < 4; ++m) xxm[m] = xxb[m0 + tj * 4 + m];
    #pragma unroll
    for (int r = 0; r < 4; ++r) {
      float xv = xxnS[ti * 4 + r];
      #pragma unroll
      for (int m = 0; m < 4; ++m)
        d2t[(ti * 4 + r) * 65 + tj * 4 + m] = xv + xxm[m] - 2.f * acc[r][m];
    }
    __syncthreads();
    // all 256 lanes scan: row = tid&63, m-slice = part*16..+16
    #pragma unroll 4
    for (int j = 0; j < 16; ++j) {
      float v = d2t[row * 65 + part * 16 + j];
      if (v < ld[19]) {
        int m = m0 + part * 16 + j;
        #pragma unroll
        for (int k = 19; k >= 1; --k) {
          bool a = v < ld[k];
          bool s = v < ld[k - 1];
          float nd = a ? (s ? ld[k - 1] : v) : ld[k];
          int   ni = a ? (s ? li[k - 1] : m) : li[k];
          ld[k] = nd; li[k] = ni;
        }
        bool a0 = v < ld[0];
        li[0] = a0 ? m : li[0];
        ld[0] = a0 ? v : ld[0];
      }
    }
    __syncthreads();
  }

  // write partial lists (partition-major so each wave writes stride-21 rows: conflict-free)
  #pragma unroll
  for (int k = 0; k < 20; ++k) {
    mrgD[(part * 64 + row) * 21 + k] = ld[k];
    mrgI[(part * 64 + row) * 21 + k] = li[k];
  }
  __syncthreads();

  if (tid < 64) {
    int h0 = 0, h1 = 0, h2 = 0, h3 = 0;
    int* op = idxout + ((long)(b * NPTS + n0 + tid)) * KNN;
    for (int k = 0; k < KNN; ++k) {
      float v0 = mrgD[(0 * 64 + tid) * 21 + h0]; int i0 = mrgI[(0 * 64 + tid) * 21 + h0];
      float v1 = mrgD[(1 * 64 + tid) * 21 + h1]; int i1 = mrgI[(1 * 64 + tid) * 21 + h1];
      float v2 = mrgD[(2 * 64 + tid) * 21 + h2]; int i2 = mrgI[(2 * 64 + tid) * 21 + h2];
      float v3 = mrgD[(3 * 64 + tid) * 21 + h3]; int i3 = mrgI[(3 * 64 + tid) * 21 + h3];
      float bv = v0; int bi = i0; int bp = 0;
      if (v1 < bv || (v1 == bv && i1 < bi)) { bv = v1; bi = i1; bp = 1; }
      if (v2 < bv || (v2 == bv && i2 < bi)) { bv = v2; bi = i2; bp = 2; }
      if (v3 < bv || (v3 == bv && i3 < bi)) { bv = v3; bi = i3; bp = 3; }
      op[k] = bi;
      h0 += (bp == 0); h1 += (bp == 1); h2 += (bp == 2); h3 += (bp == 3);
    }
  }
}

// ---------------- vsus[b][n][p] = sum_c Wp[p][c] * x[c][n] ----------------
__global__ __launch_bounds__(256) void gemm_vsus_kernel(const float* __restrict__ x,
                                                        const float* __restrict__ Wp,
                                                        float* __restrict__ out,
                                                        int C, int P2, long bstride) {
  __shared__ float xs[32 * 65];
  __shared__ float wsd[32 * 65];
  int tid = threadIdx.x;
  int b = blockIdx.z;
  int n0 = blockIdx.x * 64;
  int p0 = blockIdx.y * 64;
  const float* xb = x + (long)b * bstride;
  float acc[4][4];
  #pragma unroll
  for (int r = 0; r < 4; ++r)
    #pragma unroll
    for (int m = 0; m < 4; ++m) acc[r][m] = 0.f;
  int ti = tid >> 4, tj = tid & 15;

  for (int k0 = 0; k0 < C; k0 += 32) {
    int kcnt = min(32, C - k0);
    __syncthreads();
    for (int i = tid; i < kcnt * 64; i += 256) {
      int kc = i >> 6, j = i & 63;
      xs[kc * 65 + j] = xb[(k0 + kc) * NPTS + n0 + j];
    }
    for (int i = tid; i < kcnt * 64; i += 256) {
      int kc = i % kcnt, p = i / kcnt;
      wsd[kc * 65 + p] = Wp[(p0 + p) * C + k0 + kc];
    }
    __syncthreads();
    for (int kc = 0; kc < kcnt; ++kc) {
      float av[4], bv[4];
      #pragma unroll
      for (int r = 0; r < 4; ++r) av[r] = xs[kc * 65 + ti * 4 + r];
      #pragma unroll
      for (int m = 0; m < 4; ++m) bv[m] = wsd[kc * 65 + tj * 4 + m];
      #pragma unroll
      for (int r = 0; r < 4; ++r)
        #pragma unroll
        for (int m = 0; m < 4; ++m) acc[r][m] += av[r] * bv[m];
    }
  }
  #pragma unroll
  for (int r = 0; r < 4; ++r) {
    int n = n0 + ti * 4 + r;
    float4 v = make_float4(acc[r][0], acc[r][1], acc[r][2], acc[r][3]);
    *reinterpret_cast<float4*>(out + (long)(b * NPTS + n) * P2 + p0 + tj * 4) = v;
  }
}

// ---------------- gather + max_k + leaky -> xcat channel block ----------------
__global__ __launch_bounds__(256) void gather_max_kernel(const float* __restrict__ vsus,
                                                         const int* __restrict__ idxin,
                                                         const float* __restrict__ bias,
                                                         float* __restrict__ xcat,
                                                         int O, int cho) {
  __shared__ int idxs[32 * KNN];
  __shared__ float ot[256 * 33];
  int tid = threadIdx.x;
  int b = blockIdx.y;
  int n0 = blockIdx.x * 32;
  int P2 = 2 * O;
  for (int i = tid; i < 32 * KNN; i += 256) idxs[i] = idxin[(b * NPTS + n0) * KNN + i];
  __syncthreads();
  int G = 256 / O;
  int o = tid % O;
  int ns = tid / O;
  float bo = bias[o];
  const float* vb = vsus + (long)b * NPTS * P2;
  for (int step = 0; step < 32 / G; ++step) {
    int nn = step * G + ns;
    float mx = -1e30f;
    for (int k = 0; k < KNN; ++k) {
      int j = idxs[nn * KNN + k];
      mx = fmaxf(mx, vb[j * P2 + o]);
    }
    float us = vb[(n0 + nn) * P2 + O + o] + bo;
    ot[o * 33 + nn] = leaky(mx + us);
  }
  __syncthreads();
  float* ob = xcat + ((long)b * 512 + cho) * NPTS + n0;
  for (int i = tid; i < O * 32; i += 256) {
    int oo = i >> 5, nn = i & 31;
    ob[oo * NPTS + nn] = ot[oo * 33 + nn];
  }
}

// ---------------- mlp gemm fused with partial max/sum over n ----------------
__global__ __launch_bounds__(256) void mlp_kernel(const float* __restrict__ xcat,
                                                  const float* __restrict__ Wm,
                                                  const float* __restrict__ bvec,
                                                  float* __restrict__ pbuf) {
  __shared__ float xs[32 * 65];
  __shared__ float wsd[32 * 65];
  __shared__ float red[2 * 64 * 17];
  int tid = threadIdx.x;
  int b = blockIdx.z;
  int ot = blockIdx.y;   // 16 tiles of 64 o
  int nt = blockIdx.x;   // 4 tiles of 512 n
  int o0 = ot * 64;
  const float* xb = xcat + (long)b * 512 * NPTS;
  int ti = tid >> 4, tj = tid & 15;
  float bb[4];
  #pragma unroll
  for (int m = 0; m < 4; ++m) bb[m] = bvec[o0 + tj * 4 + m];
  float rmax[4] = {-1e30f, -1e30f, -1e30f, -1e30f};
  float rsum[4] = {0.f, 0.f, 0.f, 0.f};

  for (int nsub = 0; nsub < 8; ++nsub) {
    int n0 = nt * 512 + nsub * 64;
    float acc[4][4];
    #pragma unroll
    for (int r = 0; r < 4; ++r)
      #pragma unroll
      for (int m = 0; m < 4; ++m) acc[r][m] = 0.f;
    for (int k0 = 0; k0 < 512; k0 += 32) {
      __syncthreads();
      for (int i = tid; i < 32 * 64; i += 256) {
        int kc = i >> 6, j = i & 63;
        xs[kc * 65 + j] = xb[(k0 + kc) * NPTS + n0 + j];
      }
      for (int i = tid; i < 32 * 64; i += 256) {
        int kc = i & 31, p = i >> 5;
        wsd[kc * 65 + p] = Wm[(o0 + p) * 512 + k0 + kc];
      }
      __syncthreads();
      for (int kc = 0; kc < 32; ++kc) {
        float av[4], bv[4];
        #pragma unroll
        for (int r = 0; r < 4; ++r) av[r] = xs[kc * 65 + ti * 4 + r];
        #pragma unroll
        for (int m = 0; m < 4; ++m) bv[m] = wsd[kc * 65 + tj * 4 + m];
        #pragma unroll
        for (int r = 0; r < 4; ++r)
          #pragma unroll
          for (int m = 0; m < 4; ++m) acc[r][m] += av[r] * bv[m];
      }
    }
    #pragma unroll
    for (int r = 0; r < 4; ++r)
      #pragma unroll
      for (int m = 0; m < 4; ++m) {
        float y = leaky(acc[r][m] + bb[m]);
        rmax[m] = fmaxf(rmax[m], y);
        rsum[m] += y;
      }
  }
  __syncthreads();
  #pragma unroll
  for (int m = 0; m < 4; ++m) {
    red[(tj * 4 + m) * 17 + ti] = rmax[m];
    red[64 * 17 + (tj * 4 + m) * 17 + ti] = rsum[m];
  }
  __syncthreads();
  if (tid < 64) {
    float mx = -1e30f, s = 0.f;
    for (int i = 0; i < 16; ++i) {
      mx = fmaxf(mx, red[tid * 17 + i]);
      s += red[64 * 17 + tid * 17 + i];
    }
    float* pb = pbuf + (((b * 16 + ot) * 4 + nt) * 2) * 64;
    pb[tid] = mx;
    pb[64 + tid] = s;
  }
}

__global__ void mlp_reduce_kernel(const float* __restrict__ pbuf, float* __restrict__ feat) {
  int t = blockIdx.x * 256 + threadIdx.x;   // 8192
  int b = t >> 10, o = t & 1023;
  int ot = o >> 6, oo = o & 63;
  float mx = -1e30f, s = 0.f;
  for (int nt = 0; nt < 4; ++nt) {
    const float* pb = pbuf + (((b * 16 + ot) * 4 + nt) * 2) * 64;
    mx = fmaxf(mx, pb[oo]);
    s += pb[64 + oo];
  }
  feat[b * 2048 + o] = mx;
  feat[b * 2048 + 1024 + o] = s * (1.f / 2048.f);
}

// ---------------- fc layers: one wave per output ----------------
__global__ void fc_kernel(const float* __restrict__ X, const float* __restrict__ W,
                          const float* __restrict__ bias, const float* __restrict__ g,
                          const float* __restrict__ bb, float* __restrict__ out,
                          int B, int O, int Kdim, int hasAct) {
  int gt = blockIdx.x * 256 + threadIdx.x;
  int wid = gt >> 6;
  int lane = threadIdx.x & 63;
  if (wid >= B * O) return;
  int b = wid / O, o = wid - b * O;
  const float* xr = X + (long)b * Kdim;
  const float* wr = W + (long)o * Kdim;
  float acc = 0.f;
  for (int c = lane; c < Kdim; c += 64) acc += xr[c] * wr[c];
  for (int off = 32; off; off >>= 1) acc += __shfl_down(acc, off);
  if (lane == 0) {
    float h = acc + bias[o];
    if (hasAct) {
      float a = g[o] * rsqrtf(1.0f + 1e-5f);
      h = a * h + bb[o];
      h = fmaxf(h, 0.2f * h);
    }
    out[b * O + o] = h;
  }
}

// ---------------- launch ----------------
extern "C" void kernel_launch(void* const* d_in, const int* in_sizes, int n_in,
                              void* d_out, int out_size, void* d_ws, size_t ws_size,
                              hipStream_t stream) {
  const float* points = (const float*)d_in[0];
  char* ws = (char*)d_ws;

  const size_t XCAT = 0;                         // [8][512][2048] f
  const size_t VSUS = 33554432;                  // [8][2048][512] f
  const size_t IDXB = 67108864;                  // [8][2048][20] i
  const size_t XXB  = 68419584;                  // [8][2048] f
  const size_t WP   = 68485120;                  // [512][128] f
  const size_t WMLP = 68747264;                  // [1024][512] f
  const size_t PBUF = 70844416;                  // 65536 f
  const size_t FEAT = 71106560;                  // [8][2048] f
  const size_t H1   = 71172096;                  // [8][512] f
  const size_t H2   = 71188480;                  // [8][256] f

  float* xcat = (float*)(ws + XCAT);
  float* vsus = (float*)(ws + VSUS);
  int*   idxb = (int*)(ws + IDXB);
  float* xxb  = (float*)(ws + XXB);
  float* wp   = (float*)(ws + WP);
  float* wmlp = (float*)(ws + WMLP);
  float* pbuf = (float*)(ws + PBUF);
  float* feat = (float*)(ws + FEAT);
  float* h1   = (float*)(ws + H1);
  float* h2   = (float*)(ws + H2);

  struct Layer { const float* x; long bstride; int C, O, cho, wi, gi, bi; };
  Layer layers[4] = {
    { points,              (long)3 * NPTS,   3,   64, 0,   1, 2, 3 },
    { xcat,                (long)512 * NPTS, 64,  64, 64,  4, 5, 6 },
    { xcat + 64 * NPTS,    (long)512 * NPTS, 64,  128, 128, 7, 8, 9 },
    { xcat + 128 * NPTS,   (long)512 * NPTS, 128, 256, 256, 10, 11, 12 },
  };

  for (int L = 0; L < 4; ++L) {
    Layer& ly = layers[L];
    int P2 = 2 * ly.O;
    const float* W = (const float*)d_in[ly.wi];
    const float* g = (const float*)d_in[ly.gi];
    const float* bv = (const float*)d_in[ly.bi];

    int wtot = 2 * ly.O * ly.C;
    prep_w_kernel<<<(wtot + 255) / 256, 256, 0, stream>>>(W, g, wp, ly.O, ly.C);
    xx_kernel<<<dim3(NPTS / 256, BATCH), 256, 0, stream>>>(ly.x, xxb, ly.C, ly.bstride);
    if (ly.C == 3) {
      knn_kernel<3><<<dim3(NPTS / 64, BATCH), 256, 0, stream>>>(ly.x, xxb, idxb, ly.bstride);
    } else if (ly.C == 64) {
      knn_kernel<64><<<dim3(NPTS / 64, BATCH), 256, 0, stream>>>(ly.x, xxb, idxb, ly.bstride);
    } else {
      knn_kernel<128><<<dim3(NPTS / 64, BATCH), 256, 0, stream>>>(ly.x, xxb, idxb, ly.bstride);
    }
    gemm_vsus_kernel<<<dim3(NPTS / 64, P2 / 64, BATCH), 256, 0, stream>>>(
        ly.x, wp, vsus, ly.C, P2, ly.bstride);
    gather_max_kernel<<<dim3(NPTS / 32, BATCH), 256, 0, stream>>>(
        vsus, idxb, bv, xcat, ly.O, ly.cho);
  }

  prep_mlpw_kernel<<<(1024 * 512 + 255) / 256, 256, 0, stream>>>(
      (const float*)d_in[13], (const float*)d_in[14], wmlp);
  mlp_kernel<<<dim3(4, 16, BATCH), 256, 0, stream>>>(
      xcat, wmlp, (const float*)d_in[15], pbuf);
  mlp_reduce_kernel<<<32, 256, 0, stream>>>(pbuf, feat);

  fc_kernel<<<(BATCH * 512 * 64) / 256, 256, 0, stream>>>(
      feat, (const float*)d_in[16], (const float*)d_in[17],
      (const float*)d_in[18], (const float*)d_in[19], h1, BATCH, 512, 2048, 1);
  fc_kernel<<<(BATCH * 256 * 64) / 256, 256, 0, stream>>>(
      h1, (const float*)d_in[20], (const float*)d_in[21],
      (const float*)d_in[22], (const float*)d_in[23], h2, BATCH, 256, 512, 1);
  fc_kernel<<<(BATCH * 40 * 64) / 256, 256, 0, stream>>>(
      h2, (const float*)d_in[24], (const float*)d_in[25],
      nullptr, nullptr, (float*)d_out, BATCH, 40, 256, 0);
}

// Round 3
// 2435.124 us; speedup vs baseline: 2.6120x; 1.4437x over previous
//
#include <hip/hip_runtime.h>

#define NPTS 2048
#define BATCH 8
#define KNN 20
#define KSPLIT 4

__device__ __forceinline__ float leaky(float y) { return fmaxf(y, 0.2f * y); }

// ---------------- prep: Wp[2O][C] = [a*W1 ; a*(W2-W1)] ----------------
__global__ void prep_w_kernel(const float* __restrict__ W, const float* __restrict__ g,
                              float* __restrict__ Wp, int O, int C) {
  int t = blockIdx.x * 256 + threadIdx.x;
  if (t >= 2 * O * C) return;
  int row = t / C, c = t - row * C;
  float inv = rsqrtf(1.0f + 1e-5f);
  if (row < O) {
    Wp[t] = g[row] * inv * W[row * 2 * C + c];
  } else {
    int o = row - O;
    Wp[t] = g[o] * inv * (W[o * 2 * C + C + c] - W[o * 2 * C + c]);
  }
}

__global__ void prep_mlpw_kernel(const float* __restrict__ W, const float* __restrict__ g,
                                 float* __restrict__ Wm) {
  int t = blockIdx.x * 256 + threadIdx.x;
  if (t >= 1024 * 512) return;
  int o = t >> 9;
  Wm[t] = g[o] * rsqrtf(1.0f + 1e-5f) * W[t];
}

// ---------------- xx[b][m] = sum_c x[c][m]^2 ----------------
__global__ void xx_kernel(const float* __restrict__ x, float* __restrict__ xx,
                          int C, long bstride) {
  int b = blockIdx.y;
  int m = blockIdx.x * 256 + threadIdx.x;
  const float* xb = x + (long)b * bstride;
  float s = 0.f;
  for (int c = 0; c < C; ++c) { float v = xb[c * NPTS + m]; s += v * v; }
  xx[b * NPTS + m] = s;
}

// ---------------- knn scan: split-m partial top-20 ----------------
// grid (NPTS/64, KSPLIT, BATCH); block scans m in [s*512, (s+1)*512)
template <int C>
__global__ __launch_bounds__(256) void knn_scan(const float* __restrict__ x,
                                                const float* __restrict__ xx,
                                                float* __restrict__ pd,
                                                unsigned short* __restrict__ pi,
                                                long bstride) {
  __shared__ float smem[8384];
  float* xnT = smem;              // [32][65]
  float* xmT = smem + 2080;       // [32][65]
  float* d2t = smem + 4160;       // [64][65]
  float* xxnS = smem + 8320;      // [64]
  float* mrgD = smem;                              // alias: [4*64][21] f32 (21504 B)
  unsigned short* mrgI = (unsigned short*)(smem + 5376);  // [4*64][21] u16 (10752 B)

  int tid = threadIdx.x;
  int b = blockIdx.z;
  int sidx = blockIdx.y;
  int n0 = blockIdx.x * 64;
  const float* xb = x + (long)b * bstride;
  const float* xxb = xx + b * NPTS;

  if (tid < 64) xxnS[tid] = xxb[n0 + tid];

  float ld[20]; int li[20];
  #pragma unroll
  for (int k = 0; k < 20; ++k) { ld[k] = 1e30f; li[k] = 0x7fffffff; }

  int ti = tid >> 4, tj = tid & 15;
  int row = tid & 63, part = tid >> 6;
  int mt0 = sidx * (32 / KSPLIT);

  for (int mtl = 0; mtl < 32 / KSPLIT; ++mtl) {
    int m0 = (mt0 + mtl) * 64;
    float acc[4][4];
    #pragma unroll
    for (int r = 0; r < 4; ++r)
      #pragma unroll
      for (int m = 0; m < 4; ++m) acc[r][m] = 0.f;

    for (int k0 = 0; k0 < C; k0 += 32) {
      int kcnt = (C - k0) < 32 ? (C - k0) : 32;
      __syncthreads();
      for (int i = tid; i < kcnt * 64; i += 256) {
        int kc = i >> 6, j = i & 63;
        xnT[kc * 65 + j] = xb[(k0 + kc) * NPTS + n0 + j];
        xmT[kc * 65 + j] = xb[(k0 + kc) * NPTS + m0 + j];
      }
      __syncthreads();
      for (int kc = 0; kc < kcnt; ++kc) {
        float av[4], bv[4];
        #pragma unroll
        for (int r = 0; r < 4; ++r) av[r] = xnT[kc * 65 + ti * 4 + r];
        #pragma unroll
        for (int m = 0; m < 4; ++m) bv[m] = xmT[kc * 65 + tj * 4 + m];
        #pragma unroll
        for (int r = 0; r < 4; ++r)
          #pragma unroll
          for (int m = 0; m < 4; ++m) acc[r][m] += av[r] * bv[m];
      }
    }
    float xxm[4];
    #pragma unroll
    for (int m = 0; m < 4; ++m) xxm[m] = xxb[m0 + tj * 4 + m];
    __syncthreads();
    #pragma unroll
    for (int r = 0; r < 4; ++r) {
      float xv = xxnS[ti * 4 + r];
      #pragma unroll
      for (int m = 0; m < 4; ++m)
        d2t[(ti * 4 + r) * 65 + tj * 4 + m] = xv + xxm[m] - 2.f * acc[r][m];
    }
    __syncthreads();
    #pragma unroll 4
    for (int j = 0; j < 16; ++j) {
      float v = d2t[row * 65 + part * 16 + j];
      if (v < ld[19]) {
        int m = m0 + part * 16 + j;
        #pragma unroll
        for (int k = 19; k >= 1; --k) {
          bool a = v < ld[k];
          bool s = v < ld[k - 1];
          float nd = a ? (s ? ld[k - 1] : v) : ld[k];
          int   ni = a ? (s ? li[k - 1] : m) : li[k];
          ld[k] = nd; li[k] = ni;
        }
        bool a0 = v < ld[0];
        li[0] = a0 ? m : li[0];
        ld[0] = a0 ? v : ld[0];
      }
    }
    __syncthreads();
  }

  // write partial lists to LDS (conflict-free: stride 21 words, gcd(21,32)=1)
  #pragma unroll
  for (int k = 0; k < 20; ++k) {
    mrgD[(part * 64 + row) * 21 + k] = ld[k];
    mrgI[(part * 64 + row) * 21 + k] = (unsigned short)li[k];
  }
  __syncthreads();

  if (tid < 64) {
    int h0 = 0, h1 = 0, h2 = 0, h3 = 0;
    long obase = ((long)((b * KSPLIT + sidx) * NPTS) + n0 + tid) * KNN;
    for (int k = 0; k < KNN; ++k) {
      float v0 = mrgD[(0 * 64 + tid) * 21 + h0]; int i0 = mrgI[(0 * 64 + tid) * 21 + h0];
      float v1 = mrgD[(1 * 64 + tid) * 21 + h1]; int i1 = mrgI[(1 * 64 + tid) * 21 + h1];
      float v2 = mrgD[(2 * 64 + tid) * 21 + h2]; int i2 = mrgI[(2 * 64 + tid) * 21 + h2];
      float v3 = mrgD[(3 * 64 + tid) * 21 + h3]; int i3 = mrgI[(3 * 64 + tid) * 21 + h3];
      float bv = v0; int bi = i0; int bp = 0;
      if (v1 < bv || (v1 == bv && i1 < bi)) { bv = v1; bi = i1; bp = 1; }
      if (v2 < bv || (v2 == bv && i2 < bi)) { bv = v2; bi = i2; bp = 2; }
      if (v3 < bv || (v3 == bv && i3 < bi)) { bv = v3; bi = i3; bp = 3; }
      pd[obase + k] = bv;
      pi[obase + k] = (unsigned short)bi;
      h0 += (bp == 0); h1 += (bp == 1); h2 += (bp == 2); h3 += (bp == 3);
    }
  }
}

// ---------------- knn merge: 4 partial lists -> final top-20 indices ----------------
__global__ void knn_merge(const float* __restrict__ pd, const unsigned short* __restrict__ pi,
                          int* __restrict__ idxout) {
  int t = blockIdx.x * 256 + threadIdx.x;   // b*NPTS + n, total 16384
  int b = t >> 11, n = t & 2047;
  long base[KSPLIT]; int h[KSPLIT];
  #pragma unroll
  for (int s = 0; s < KSPLIT; ++s) {
    base[s] = ((long)((b * KSPLIT + s) * NPTS) + n) * KNN;
    h[s] = 0;
  }
  int* op = idxout + (long)t * KNN;
  for (int k = 0; k < KNN; ++k) {
    float bv = 1e38f; int bi = 0x7fffffff; int bs = 0;
    #pragma unroll
    for (int s = 0; s < KSPLIT; ++s) {
      float v = pd[base[s] + h[s]];
      int i = pi[base[s] + h[s]];
      if (v < bv || (v == bv && i < bi)) { bv = v; bi = i; bs = s; }
    }
    op[k] = bi;
    #pragma unroll
    for (int s = 0; s < KSPLIT; ++s) h[s] += (bs == s);
  }
}

// ---------------- vsus[b][n][p] = sum_c Wp[p][c] * x[c][n] ----------------
__global__ __launch_bounds__(256) void gemm_vsus_kernel(const float* __restrict__ x,
                                                        const float* __restrict__ Wp,
                                                        float* __restrict__ out,
                                                        int C, int P2, long bstride) {
  __shared__ float xs[32 * 65];
  __shared__ float wsd[32 * 65];
  int tid = threadIdx.x;
  int b = blockIdx.z;
  int n0 = blockIdx.x * 64;
  int p0 = blockIdx.y * 64;
  const float* xb = x + (long)b * bstride;
  float acc[4][4];
  #pragma unroll
  for (int r = 0; r < 4; ++r)
    #pragma unroll
    for (int m = 0; m < 4; ++m) acc[r][m] = 0.f;
  int ti = tid >> 4, tj = tid & 15;

  for (int k0 = 0; k0 < C; k0 += 32) {
    int kcnt = min(32, C - k0);
    __syncthreads();
    for (int i = tid; i < kcnt * 64; i += 256) {
      int kc = i >> 6, j = i & 63;
      xs[kc * 65 + j] = xb[(k0 + kc) * NPTS + n0 + j];
    }
    for (int i = tid; i < kcnt * 64; i += 256) {
      int kc = i % kcnt, p = i / kcnt;
      wsd[kc * 65 + p] = Wp[(p0 + p) * C + k0 + kc];
    }
    __syncthreads();
    for (int kc = 0; kc < kcnt; ++kc) {
      float av[4], bv[4];
      #pragma unroll
      for (int r = 0; r < 4; ++r) av[r] = xs[kc * 65 + ti * 4 + r];
      #pragma unroll
      for (int m = 0; m < 4; ++m) bv[m] = wsd[kc * 65 + tj * 4 + m];
      #pragma unroll
      for (int r = 0; r < 4; ++r)
        #pragma unroll
        for (int m = 0; m < 4; ++m) acc[r][m] += av[r] * bv[m];
    }
  }
  #pragma unroll
  for (int r = 0; r < 4; ++r) {
    int n = n0 + ti * 4 + r;
    float4 v = make_float4(acc[r][0], acc[r][1], acc[r][2], acc[r][3]);
    *reinterpret_cast<float4*>(out + (long)(b * NPTS + n) * P2 + p0 + tj * 4) = v;
  }
}

// ---------------- gather + max_k + leaky -> xcat channel block ----------------
__global__ __launch_bounds__(256) void gather_max_kernel(const float* __restrict__ vsus,
                                                         const int* __restrict__ idxin,
                                                         const float* __restrict__ bias,
                                                         float* __restrict__ xcat,
                                                         int O, int cho) {
  __shared__ int idxs[32 * KNN];
  __shared__ float ot[256 * 33];
  int tid = threadIdx.x;
  int b = blockIdx.y;
  int n0 = blockIdx.x * 32;
  int P2 = 2 * O;
  for (int i = tid; i < 32 * KNN; i += 256) idxs[i] = idxin[(b * NPTS + n0) * KNN + i];
  __syncthreads();
  int G = 256 / O;
  int o = tid % O;
  int ns = tid / O;
  float bo = bias[o];
  const float* vb = vsus + (long)b * NPTS * P2;
  for (int step = 0; step < 32 / G; ++step) {
    int nn = step * G + ns;
    float mx = -1e30f;
    for (int k = 0; k < KNN; ++k) {
      int j = idxs[nn * KNN + k];
      mx = fmaxf(mx, vb[j * P2 + o]);
    }
    float us = vb[(n0 + nn) * P2 + O + o] + bo;
    ot[o * 33 + nn] = leaky(mx + us);
  }
  __syncthreads();
  float* ob = xcat + ((long)b * 512 + cho) * NPTS + n0;
  for (int i = tid; i < O * 32; i += 256) {
    int oo = i >> 5, nn = i & 31;
    ob[oo * NPTS + nn] = ot[oo * 33 + nn];
  }
}

// ---------------- mlp gemm fused with partial max/sum over n ----------------
__global__ __launch_bounds__(256) void mlp_kernel(const float* __restrict__ xcat,
                                                  const float* __restrict__ Wm,
                                                  const float* __restrict__ bvec,
                                                  float* __restrict__ pbuf) {
  __shared__ float xs[32 * 65];
  __shared__ float wsd[32 * 65];
  __shared__ float red[2 * 64 * 17];
  int tid = threadIdx.x;
  int b = blockIdx.z;
  int ot = blockIdx.y;   // 16 tiles of 64 o
  int nt = blockIdx.x;   // 4 tiles of 512 n
  int o0 = ot * 64;
  const float* xb = xcat + (long)b * 512 * NPTS;
  int ti = tid >> 4, tj = tid & 15;
  float bb[4];
  #pragma unroll
  for (int m = 0; m < 4; ++m) bb[m] = bvec[o0 + tj * 4 + m];
  float rmax[4] = {-1e30f, -1e30f, -1e30f, -1e30f};
  float rsum[4] = {0.f, 0.f, 0.f, 0.f};

  for (int nsub = 0; nsub < 8; ++nsub) {
    int n0 = nt * 512 + nsub * 64;
    float acc[4][4];
    #pragma unroll
    for (int r = 0; r < 4; ++r)
      #pragma unroll
      for (int m = 0; m < 4; ++m) acc[r][m] = 0.f;
    for (int k0 = 0; k0 < 512; k0 += 32) {
      __syncthreads();
      for (int i = tid; i < 32 * 64; i += 256) {
        int kc = i >> 6, j = i & 63;
        xs[kc * 65 + j] = xb[(k0 + kc) * NPTS + n0 + j];
      }
      for (int i = tid; i < 32 * 64; i += 256) {
        int kc = i & 31, p = i >> 5;
        wsd[kc * 65 + p] = Wm[(o0 + p) * 512 + k0 + kc];
      }
      __syncthreads();
      for (int kc = 0; kc < 32; ++kc) {
        float av[4], bv[4];
        #pragma unroll
        for (int r = 0; r < 4; ++r) av[r] = xs[kc * 65 + ti * 4 + r];
        #pragma unroll
        for (int m = 0; m < 4; ++m) bv[m] = wsd[kc * 65 + tj * 4 + m];
        #pragma unroll
        for (int r = 0; r < 4; ++r)
          #pragma unroll
          for (int m = 0; m < 4; ++m) acc[r][m] += av[r] * bv[m];
      }
    }
    #pragma unroll
    for (int r = 0; r < 4; ++r)
      #pragma unroll
      for (int m = 0; m < 4; ++m) {
        float y = leaky(acc[r][m] + bb[m]);
        rmax[m] = fmaxf(rmax[m], y);
        rsum[m] += y;
      }
  }
  __syncthreads();
  #pragma unroll
  for (int m = 0; m < 4; ++m) {
    red[(tj * 4 + m) * 17 + ti] = rmax[m];
    red[64 * 17 + (tj * 4 + m) * 17 + ti] = rsum[m];
  }
  __syncthreads();
  if (tid < 64) {
    float mx = -1e30f, s = 0.f;
    for (int i = 0; i < 16; ++i) {
      mx = fmaxf(mx, red[tid * 17 + i]);
      s += red[64 * 17 + tid * 17 + i];
    }
    float* pb = pbuf + (((b * 16 + ot) * 4 + nt) * 2) * 64;
    pb[tid] = mx;
    pb[64 + tid] = s;
  }
}

__global__ void mlp_reduce_kernel(const float* __restrict__ pbuf, float* __restrict__ feat) {
  int t = blockIdx.x * 256 + threadIdx.x;   // 8192
  int b = t >> 10, o = t & 1023;
  int ot = o >> 6, oo = o & 63;
  float mx = -1e30f, s = 0.f;
  for (int nt = 0; nt < 4; ++nt) {
    const float* pb = pbuf + (((b * 16 + ot) * 4 + nt) * 2) * 64;
    mx = fmaxf(mx, pb[oo]);
    s += pb[64 + oo];
  }
  feat[b * 2048 + o] = mx;
  feat[b * 2048 + 1024 + o] = s * (1.f / 2048.f);
}

// ---------------- fc layers: one wave per output ----------------
__global__ void fc_kernel(const float* __restrict__ X, const float* __restrict__ W,
                          const float* __restrict__ bias, const float* __restrict__ g,
                          const float* __restrict__ bb, float* __restrict__ out,
                          int B, int O, int Kdim, int hasAct) {
  int gt = blockIdx.x * 256 + threadIdx.x;
  int wid = gt >> 6;
  int lane = threadIdx.x & 63;
  if (wid >= B * O) return;
  int b = wid / O, o = wid - b * O;
  const float* xr = X + (long)b * Kdim;
  const float* wr = W + (long)o * Kdim;
  float acc = 0.f;
  for (int c = lane; c < Kdim; c += 64) acc += xr[c] * wr[c];
  for (int off = 32; off; off >>= 1) acc += __shfl_down(acc, off);
  if (lane == 0) {
    float h = acc + bias[o];
    if (hasAct) {
      float a = g[o] * rsqrtf(1.0f + 1e-5f);
      h = a * h + bb[o];
      h = fmaxf(h, 0.2f * h);
    }
    out[b * O + o] = h;
  }
}

// ---------------- launch ----------------
extern "C" void kernel_launch(void* const* d_in, const int* in_sizes, int n_in,
                              void* d_out, int out_size, void* d_ws, size_t ws_size,
                              hipStream_t stream) {
  const float* points = (const float*)d_in[0];
  char* ws = (char*)d_ws;

  const size_t XCAT = 0;                         // [8][512][2048] f
  const size_t VSUS = 33554432;                  // [8][2048][512] f (also knn partials)
  const size_t IDXB = 67108864;                  // [8][2048][20] i
  const size_t XXB  = 68419584;                  // [8][2048] f
  const size_t WP   = 68485120;                  // [512][128] f
  const size_t WMLP = 68747264;                  // [1024][512] f
  const size_t PBUF = 70844416;                  // 65536 f
  const size_t FEAT = 71106560;                  // [8][2048] f
  const size_t H1   = 71172096;                  // [8][512] f
  const size_t H2   = 71188480;                  // [8][256] f

  float* xcat = (float*)(ws + XCAT);
  float* vsus = (float*)(ws + VSUS);
  int*   idxb = (int*)(ws + IDXB);
  float* xxb  = (float*)(ws + XXB);
  float* wp   = (float*)(ws + WP);
  float* wmlp = (float*)(ws + WMLP);
  float* pbuf = (float*)(ws + PBUF);
  float* feat = (float*)(ws + FEAT);
  float* h1   = (float*)(ws + H1);
  float* h2   = (float*)(ws + H2);

  // knn partial lists overlap the vsus region (dead until gemm_vsus)
  float* knnD = (float*)(ws + VSUS);                         // 8*4*2048*20 f = 5.24 MB
  unsigned short* knnI = (unsigned short*)(ws + VSUS + 5242880);  // 2.62 MB

  struct Layer { const float* x; long bstride; int C, O, cho, wi, gi, bi; };
  Layer layers[4] = {
    { points,              (long)3 * NPTS,   3,   64, 0,   1, 2, 3 },
    { xcat,                (long)512 * NPTS, 64,  64, 64,  4, 5, 6 },
    { xcat + 64 * NPTS,    (long)512 * NPTS, 64,  128, 128, 7, 8, 9 },
    { xcat + 128 * NPTS,   (long)512 * NPTS, 128, 256, 256, 10, 11, 12 },
  };

  for (int L = 0; L < 4; ++L) {
    Layer& ly = layers[L];
    int P2 = 2 * ly.O;
    const float* W = (const float*)d_in[ly.wi];
    const float* g = (const float*)d_in[ly.gi];
    const float* bv = (const float*)d_in[ly.bi];

    int wtot = 2 * ly.O * ly.C;
    prep_w_kernel<<<(wtot + 255) / 256, 256, 0, stream>>>(W, g, wp, ly.O, ly.C);
    xx_kernel<<<dim3(NPTS / 256, BATCH), 256, 0, stream>>>(ly.x, xxb, ly.C, ly.bstride);
    dim3 sg(NPTS / 64, KSPLIT, BATCH);
    if (ly.C == 3) {
      knn_scan<3><<<sg, 256, 0, stream>>>(ly.x, xxb, knnD, knnI, ly.bstride);
    } else if (ly.C == 64) {
      knn_scan<64><<<sg, 256, 0, stream>>>(ly.x, xxb, knnD, knnI, ly.bstride);
    } else {
      knn_scan<128><<<sg, 256, 0, stream>>>(ly.x, xxb, knnD, knnI, ly.bstride);
    }
    knn_merge<<<(BATCH * NPTS) / 256, 256, 0, stream>>>(knnD, knnI, idxb);
    gemm_vsus_kernel<<<dim3(NPTS / 64, P2 / 64, BATCH), 256, 0, stream>>>(
        ly.x, wp, vsus, ly.C, P2, ly.bstride);
    gather_max_kernel<<<dim3(NPTS / 32, BATCH), 256, 0, stream>>>(
        vsus, idxb, bv, xcat, ly.O, ly.cho);
  }

  prep_mlpw_kernel<<<(1024 * 512 + 255) / 256, 256, 0, stream>>>(
      (const float*)d_in[13], (const float*)d_in[14], wmlp);
  mlp_kernel<<<dim3(4, 16, BATCH), 256, 0, stream>>>(
      xcat, wmlp, (const float*)d_in[15], pbuf);
  mlp_reduce_kernel<<<32, 256, 0, stream>>>(pbuf, feat);

  fc_kernel<<<(BATCH * 512 * 64) / 256, 256, 0, stream>>>(
      feat, (const float*)d_in[16], (const float*)d_in[17],
      (const float*)d_in[18], (const float*)d_in[19], h1, BATCH, 512, 2048, 1);
  fc_kernel<<<(BATCH * 256 * 64) / 256, 256, 0, stream>>>(
      h1, (const float*)d_in[20], (const float*)d_in[21],
      (const float*)d_in[22], (const float*)d_in[23], h2, BATCH, 256, 512, 1);
  fc_kernel<<<(BATCH * 40 * 64) / 256, 256, 0, stream>>>(
      h2, (const float*)d_in[24], (const float*)d_in[25],
      nullptr, nullptr, (float*)d_out, BATCH, 40, 256, 0);
}

// Round 4
// 1887.614 us; speedup vs baseline: 3.3697x; 1.2901x over previous
//
#include <hip/hip_runtime.h>

#define NPTS 2048
#define BATCH 8
#define KNN 20
#define KSPLIT 4

__device__ __forceinline__ float leaky(float y) { return fmaxf(y, 0.2f * y); }

// ---------------- prep: Wp[2O][C] = [a*W1 ; a*(W2-W1)] ----------------
__global__ void prep_w_kernel(const float* __restrict__ W, const float* __restrict__ g,
                              float* __restrict__ Wp, int O, int C) {
  int t = blockIdx.x * 256 + threadIdx.x;
  if (t >= 2 * O * C) return;
  int row = t / C, c = t - row * C;
  float inv = rsqrtf(1.0f + 1e-5f);
  if (row < O) {
    Wp[t] = g[row] * inv * W[row * 2 * C + c];
  } else {
    int o = row - O;
    Wp[t] = g[o] * inv * (W[o * 2 * C + C + c] - W[o * 2 * C + c]);
  }
}

// prep mlp weight: transpose to k-major, fold bn scale. Wt[k][o], k<512, o<1024
__global__ void prep_mlpw_kernel(const float* __restrict__ W, const float* __restrict__ g,
                                 float* __restrict__ Wt) {
  __shared__ float tile[32][33];
  int k0 = blockIdx.x * 32;   // 16
  int o0 = blockIdx.y * 32;   // 32
  int tx = threadIdx.x & 31, tyq = threadIdx.x >> 5;
  for (int r = tyq; r < 32; r += 8)
    tile[r][tx] = W[(o0 + r) * 512 + k0 + tx];
  __syncthreads();
  float inv = rsqrtf(1.0f + 1e-5f);
  for (int r = tyq; r < 32; r += 8) {
    int k = k0 + r, o = o0 + tx;
    Wt[k * 1024 + o] = g[o] * inv * tile[tx][r];
  }
}

// ---------------- xx[b][m] = sum_c x[c][m]^2 ----------------
__global__ void xx_kernel(const float* __restrict__ x, float* __restrict__ xx,
                          int C, long bstride) {
  int b = blockIdx.y;
  int m = blockIdx.x * 256 + threadIdx.x;
  const float* xb = x + (long)b * bstride;
  float s = 0.f;
  for (int c = 0; c < C; ++c) { float v = xb[c * NPTS + m]; s += v * v; }
  xx[b * NPTS + m] = s;
}

// ---------------- knn scan: split-m partial top-20 ----------------
template <int C>
__global__ __launch_bounds__(256) void knn_scan(const float* __restrict__ x,
                                                const float* __restrict__ xx,
                                                float* __restrict__ pd,
                                                unsigned short* __restrict__ pi,
                                                long bstride) {
  __shared__ float smem[8384];
  float* xnT = smem;              // [32][65]
  float* xmT = smem + 2080;       // [32][65]
  float* d2t = smem + 4160;       // [64][65]
  float* xxnS = smem + 8320;      // [64]
  float* mrgD = smem;                              // alias: [4*64][21] f32
  unsigned short* mrgI = (unsigned short*)(smem + 5376);  // [4*64][21] u16

  int tid = threadIdx.x;
  int b = blockIdx.z;
  int sidx = blockIdx.y;
  int n0 = blockIdx.x * 64;
  const float* xb = x + (long)b * bstride;
  const float* xxb = xx + b * NPTS;

  if (tid < 64) xxnS[tid] = xxb[n0 + tid];

  float ld[20]; int li[20];
  #pragma unroll
  for (int k = 0; k < 20; ++k) { ld[k] = 1e30f; li[k] = 0x7fffffff; }

  int ti = tid >> 4, tj = tid & 15;
  int row = tid & 63, part = tid >> 6;
  int mt0 = sidx * (32 / KSPLIT);

  for (int mtl = 0; mtl < 32 / KSPLIT; ++mtl) {
    int m0 = (mt0 + mtl) * 64;
    float acc[4][4];
    #pragma unroll
    for (int r = 0; r < 4; ++r)
      #pragma unroll
      for (int m = 0; m < 4; ++m) acc[r][m] = 0.f;

    for (int k0 = 0; k0 < C; k0 += 32) {
      int kcnt = (C - k0) < 32 ? (C - k0) : 32;
      __syncthreads();
      for (int i = tid; i < kcnt * 64; i += 256) {
        int kc = i >> 6, j = i & 63;
        xnT[kc * 65 + j] = xb[(k0 + kc) * NPTS + n0 + j];
        xmT[kc * 65 + j] = xb[(k0 + kc) * NPTS + m0 + j];
      }
      __syncthreads();
      for (int kc = 0; kc < kcnt; ++kc) {
        float av[4], bv[4];
        #pragma unroll
        for (int r = 0; r < 4; ++r) av[r] = xnT[kc * 65 + ti * 4 + r];
        #pragma unroll
        for (int m = 0; m < 4; ++m) bv[m] = xmT[kc * 65 + tj * 4 + m];
        #pragma unroll
        for (int r = 0; r < 4; ++r)
          #pragma unroll
          for (int m = 0; m < 4; ++m) acc[r][m] += av[r] * bv[m];
      }
    }
    float xxm[4];
    #pragma unroll
    for (int m = 0; m < 4; ++m) xxm[m] = xxb[m0 + tj * 4 + m];
    __syncthreads();
    #pragma unroll
    for (int r = 0; r < 4; ++r) {
      float xv = xxnS[ti * 4 + r];
      #pragma unroll
      for (int m = 0; m < 4; ++m)
        d2t[(ti * 4 + r) * 65 + tj * 4 + m] = xv + xxm[m] - 2.f * acc[r][m];
    }
    __syncthreads();
    #pragma unroll 4
    for (int j = 0; j < 16; ++j) {
      float v = d2t[row * 65 + part * 16 + j];
      if (v < ld[19]) {
        int m = m0 + part * 16 + j;
        #pragma unroll
        for (int k = 19; k >= 1; --k) {
          bool a = v < ld[k];
          bool s = v < ld[k - 1];
          float nd = a ? (s ? ld[k - 1] : v) : ld[k];
          int   ni = a ? (s ? li[k - 1] : m) : li[k];
          ld[k] = nd; li[k] = ni;
        }
        bool a0 = v < ld[0];
        li[0] = a0 ? m : li[0];
        ld[0] = a0 ? v : ld[0];
      }
    }
    __syncthreads();
  }

  #pragma unroll
  for (int k = 0; k < 20; ++k) {
    mrgD[(part * 64 + row) * 21 + k] = ld[k];
    mrgI[(part * 64 + row) * 21 + k] = (unsigned short)li[k];
  }
  __syncthreads();

  if (tid < 64) {
    int h0 = 0, h1 = 0, h2 = 0, h3 = 0;
    long obase = ((long)((b * KSPLIT + sidx) * NPTS) + n0 + tid) * KNN;
    for (int k = 0; k < KNN; ++k) {
      float v0 = mrgD[(0 * 64 + tid) * 21 + h0]; int i0 = mrgI[(0 * 64 + tid) * 21 + h0];
      float v1 = mrgD[(1 * 64 + tid) * 21 + h1]; int i1 = mrgI[(1 * 64 + tid) * 21 + h1];
      float v2 = mrgD[(2 * 64 + tid) * 21 + h2]; int i2 = mrgI[(2 * 64 + tid) * 21 + h2];
      float v3 = mrgD[(3 * 64 + tid) * 21 + h3]; int i3 = mrgI[(3 * 64 + tid) * 21 + h3];
      float bv = v0; int bi = i0; int bp = 0;
      if (v1 < bv || (v1 == bv && i1 < bi)) { bv = v1; bi = i1; bp = 1; }
      if (v2 < bv || (v2 == bv && i2 < bi)) { bv = v2; bi = i2; bp = 2; }
      if (v3 < bv || (v3 == bv && i3 < bi)) { bv = v3; bi = i3; bp = 3; }
      pd[obase + k] = bv;
      pi[obase + k] = (unsigned short)bi;
      h0 += (bp == 0); h1 += (bp == 1); h2 += (bp == 2); h3 += (bp == 3);
    }
  }
}

// ---------------- knn merge ----------------
__global__ void knn_merge(const float* __restrict__ pd, const unsigned short* __restrict__ pi,
                          int* __restrict__ idxout) {
  int t = blockIdx.x * 256 + threadIdx.x;
  int b = t >> 11, n = t & 2047;
  long base[KSPLIT]; int h[KSPLIT];
  #pragma unroll
  for (int s = 0; s < KSPLIT; ++s) {
    base[s] = ((long)((b * KSPLIT + s) * NPTS) + n) * KNN;
    h[s] = 0;
  }
  int* op = idxout + (long)t * KNN;
  for (int k = 0; k < KNN; ++k) {
    float bv = 1e38f; int bi = 0x7fffffff; int bs = 0;
    #pragma unroll
    for (int s = 0; s < KSPLIT; ++s) {
      float v = pd[base[s] + h[s]];
      int i = pi[base[s] + h[s]];
      if (v < bv || (v == bv && i < bi)) { bv = v; bi = i; bs = s; }
    }
    op[k] = bi;
    #pragma unroll
    for (int s = 0; s < KSPLIT; ++s) h[s] += (bs == s);
  }
}

// ---------------- vsus[b][n][p] = sum_c Wp[p][c] * x[c][n] ----------------
__global__ __launch_bounds__(256) void gemm_vsus_kernel(const float* __restrict__ x,
                                                        const float* __restrict__ Wp,
                                                        float* __restrict__ out,
                                                        int C, int P2, long bstride) {
  __shared__ float xs[32 * 65];
  __shared__ float wsd[32 * 65];
  int tid = threadIdx.x;
  int b = blockIdx.z;
  int n0 = blockIdx.x * 64;
  int p0 = blockIdx.y * 64;
  const float* xb = x + (long)b * bstride;
  float acc[4][4];
  #pragma unroll
  for (int r = 0; r < 4; ++r)
    #pragma unroll
    for (int m = 0; m < 4; ++m) acc[r][m] = 0.f;
  int ti = tid >> 4, tj = tid & 15;

  for (int k0 = 0; k0 < C; k0 += 32) {
    int kcnt = min(32, C - k0);
    __syncthreads();
    for (int i = tid; i < kcnt * 64; i += 256) {
      int kc = i >> 6, j = i & 63;
      xs[kc * 65 + j] = xb[(k0 + kc) * NPTS + n0 + j];
    }
    for (int i = tid; i < kcnt * 64; i += 256) {
      int kc = i % kcnt, p = i / kcnt;
      wsd[kc * 65 + p] = Wp[(p0 + p) * C + k0 + kc];
    }
    __syncthreads();
    for (int kc = 0; kc < kcnt; ++kc) {
      float av[4], bv[4];
      #pragma unroll
      for (int r = 0; r < 4; ++r) av[r] = xs[kc * 65 + ti * 4 + r];
      #pragma unroll
      for (int m = 0; m < 4; ++m) bv[m] = wsd[kc * 65 + tj * 4 + m];
      #pragma unroll
      for (int r = 0; r < 4; ++r)
        #pragma unroll
        for (int m = 0; m < 4; ++m) acc[r][m] += av[r] * bv[m];
    }
  }
  #pragma unroll
  for (int r = 0; r < 4; ++r) {
    int n = n0 + ti * 4 + r;
    float4 v = make_float4(acc[r][0], acc[r][1], acc[r][2], acc[r][3]);
    *reinterpret_cast<float4*>(out + (long)(b * NPTS + n) * P2 + p0 + tj * 4) = v;
  }
}

// ---------------- gather + max_k + leaky -> xcat channel block ----------------
__global__ __launch_bounds__(256) void gather_max_kernel(const float* __restrict__ vsus,
                                                         const int* __restrict__ idxin,
                                                         const float* __restrict__ bias,
                                                         float* __restrict__ xcat,
                                                         int O, int cho) {
  __shared__ int idxs[32 * KNN];
  __shared__ float ot[256 * 33];
  int tid = threadIdx.x;
  int b = blockIdx.y;
  int n0 = blockIdx.x * 32;
  int P2 = 2 * O;
  for (int i = tid; i < 32 * KNN; i += 256) idxs[i] = idxin[(b * NPTS + n0) * KNN + i];
  __syncthreads();
  int G = 256 / O;
  int o = tid % O;
  int ns = tid / O;
  float bo = bias[o];
  const float* vb = vsus + (long)b * NPTS * P2;
  for (int step = 0; step < 32 / G; ++step) {
    int nn = step * G + ns;
    float mx = -1e30f;
    for (int k = 0; k < KNN; ++k) {
      int j = idxs[nn * KNN + k];
      mx = fmaxf(mx, vb[j * P2 + o]);
    }
    float us = vb[(n0 + nn) * P2 + O + o] + bo;
    ot[o * 33 + nn] = leaky(mx + us);
  }
  __syncthreads();
  float* ob = xcat + ((long)b * 512 + cho) * NPTS + n0;
  for (int i = tid; i < O * 32; i += 256) {
    int oo = i >> 5, nn = i & 31;
    ob[oo * NPTS + nn] = ot[oo * 33 + nn];
  }
}

// ---------------- mlp: 128x128 tile, 8x8/thread, fused max/sum partials ----------------
__global__ __launch_bounds__(256) void mlp_kernel(const float* __restrict__ xcat,
                                                  const float* __restrict__ Wt,
                                                  const float* __restrict__ bvec,
                                                  float* __restrict__ pbuf) {
  __shared__ float As[32][132];
  __shared__ float Bs[32][132];
  int tid = threadIdx.x;
  int b = blockIdx.z;
  int ob = blockIdx.y;       // 8 o-tiles of 128
  int nt = blockIdx.x;       // 16 n-tiles of 128
  int o0 = ob * 128, n0 = nt * 128;
  const float* xb = xcat + (long)b * 512 * NPTS;
  int ty = tid >> 4, tx = tid & 15;

  float acc[2][4][2][4];
  #pragma unroll
  for (int q = 0; q < 2; ++q)
    #pragma unroll
    for (int j = 0; j < 4; ++j)
      #pragma unroll
      for (int p = 0; p < 2; ++p)
        #pragma unroll
        for (int i = 0; i < 4; ++i) acc[q][j][p][i] = 0.f;

  for (int k0 = 0; k0 < 512; k0 += 32) {
    __syncthreads();
    #pragma unroll
    for (int s = 0; s < 4; ++s) {
      int f4 = s * 256 + tid;
      int row = f4 >> 5, c4 = f4 & 31;
      *reinterpret_cast<float4*>(&As[row][c4 * 4]) =
          *reinterpret_cast<const float4*>(&Wt[(long)(k0 + row) * 1024 + o0 + c4 * 4]);
      *reinterpret_cast<float4*>(&Bs[row][c4 * 4]) =
          *reinterpret_cast<const float4*>(&xb[(long)(k0 + row) * NPTS + n0 + c4 * 4]);
    }
    __syncthreads();
    #pragma unroll 8
    for (int kc = 0; kc < 32; ++kc) {
      float av[2][4], bv[2][4];
      *reinterpret_cast<float4*>(av[0]) = *reinterpret_cast<const float4*>(&As[kc][ty * 4]);
      *reinterpret_cast<float4*>(av[1]) = *reinterpret_cast<const float4*>(&As[kc][64 + ty * 4]);
      *reinterpret_cast<float4*>(bv[0]) = *reinterpret_cast<const float4*>(&Bs[kc][tx * 4]);
      *reinterpret_cast<float4*>(bv[1]) = *reinterpret_cast<const float4*>(&Bs[kc][64 + tx * 4]);
      #pragma unroll
      for (int q = 0; q < 2; ++q)
        #pragma unroll
        for (int j = 0; j < 4; ++j)
          #pragma unroll
          for (int p = 0; p < 2; ++p)
            #pragma unroll
            for (int i = 0; i < 4; ++i) acc[q][j][p][i] += av[q][j] * bv[p][i];
    }
  }

  // epilogue: bias + leaky, then per-thread max/sum over 8 n's, reduce over tx group
  float rmax[2][4], rsum[2][4];
  #pragma unroll
  for (int q = 0; q < 2; ++q)
    #pragma unroll
    for (int j = 0; j < 4; ++j) {
      float bb = bvec[o0 + q * 64 + ty * 4 + j];
      float mx = -1e30f, sm = 0.f;
      #pragma unroll
      for (int p = 0; p < 2; ++p)
        #pragma unroll
        for (int i = 0; i < 4; ++i) {
          float y = leaky(acc[q][j][p][i] + bb);
          mx = fmaxf(mx, y);
          sm += y;
        }
      rmax[q][j] = mx;
      rsum[q][j] = sm;
    }
  #pragma unroll
  for (int off = 8; off; off >>= 1) {
    #pragma unroll
    for (int q = 0; q < 2; ++q)
      #pragma unroll
      for (int j = 0; j < 4; ++j) {
        rmax[q][j] = fmaxf(rmax[q][j], __shfl_xor(rmax[q][j], off));
        rsum[q][j] += __shfl_xor(rsum[q][j], off);
      }
  }
  if (tx == 0) {
    float* pb = pbuf + (((long)(b * 8 + ob) * 16 + nt) * 2) * 128;
    #pragma unroll
    for (int q = 0; q < 2; ++q)
      #pragma unroll
      for (int j = 0; j < 4; ++j) {
        int ol = q * 64 + ty * 4 + j;
        pb[ol] = rmax[q][j];
        pb[128 + ol] = rsum[q][j];
      }
  }
}

__global__ void mlp_reduce_kernel(const float* __restrict__ pbuf, float* __restrict__ feat) {
  int t = blockIdx.x * 256 + threadIdx.x;   // 8192
  int b = t >> 10, o = t & 1023;
  int ob = o >> 7, ol = o & 127;
  float mx = -1e30f, s = 0.f;
  for (int nt = 0; nt < 16; ++nt) {
    const float* pb = pbuf + (((long)(b * 8 + ob) * 16 + nt) * 2) * 128;
    mx = fmaxf(mx, pb[ol]);
    s += pb[128 + ol];
  }
  feat[b * 2048 + o] = mx;
  feat[b * 2048 + 1024 + o] = s * (1.f / 2048.f);
}

// ---------------- fc layers: one wave per output ----------------
__global__ void fc_kernel(const float* __restrict__ X, const float* __restrict__ W,
                          const float* __restrict__ bias, const float* __restrict__ g,
                          const float* __restrict__ bb, float* __restrict__ out,
                          int B, int O, int Kdim, int hasAct) {
  int gt = blockIdx.x * 256 + threadIdx.x;
  int wid = gt >> 6;
  int lane = threadIdx.x & 63;
  if (wid >= B * O) return;
  int b = wid / O, o = wid - b * O;
  const float* xr = X + (long)b * Kdim;
  const float* wr = W + (long)o * Kdim;
  float acc = 0.f;
  for (int c = lane; c < Kdim; c += 64) acc += xr[c] * wr[c];
  for (int off = 32; off; off >>= 1) acc += __shfl_down(acc, off);
  if (lane == 0) {
    float h = acc + bias[o];
    if (hasAct) {
      float a = g[o] * rsqrtf(1.0f + 1e-5f);
      h = a * h + bb[o];
      h = fmaxf(h, 0.2f * h);
    }
    out[b * O + o] = h;
  }
}

// ---------------- launch ----------------
extern "C" void kernel_launch(void* const* d_in, const int* in_sizes, int n_in,
                              void* d_out, int out_size, void* d_ws, size_t ws_size,
                              hipStream_t stream) {
  const float* points = (const float*)d_in[0];
  char* ws = (char*)d_ws;

  const size_t XCAT = 0;                         // [8][512][2048] f
  const size_t VSUS = 33554432;                  // [8][2048][512] f (also knn partials, mlp pbuf)
  const size_t IDXB = 67108864;                  // [8][2048][20] i
  const size_t XXB  = 68419584;                  // [8][2048] f
  const size_t WP   = 68485120;                  // [512][128] f
  const size_t WMLP = 68747264;                  // [512][1024] f (k-major)
  const size_t FEAT = 71106560;                  // [8][2048] f
  const size_t H1   = 71172096;                  // [8][512] f
  const size_t H2   = 71188480;                  // [8][256] f

  float* xcat = (float*)(ws + XCAT);
  float* vsus = (float*)(ws + VSUS);
  int*   idxb = (int*)(ws + IDXB);
  float* xxb  = (float*)(ws + XXB);
  float* wp   = (float*)(ws + WP);
  float* wmlp = (float*)(ws + WMLP);
  float* feat = (float*)(ws + FEAT);
  float* h1   = (float*)(ws + H1);
  float* h2   = (float*)(ws + H2);

  // knn partial lists + mlp partials overlap the vsus region (stream-ordered reuse)
  float* knnD = (float*)(ws + VSUS);
  unsigned short* knnI = (unsigned short*)(ws + VSUS + 5242880);
  float* pbuf = (float*)(ws + VSUS);             // 1 MB, used after vsus is dead

  struct Layer { const float* x; long bstride; int C, O, cho, wi, gi, bi; };
  Layer layers[4] = {
    { points,              (long)3 * NPTS,   3,   64, 0,   1, 2, 3 },
    { xcat,                (long)512 * NPTS, 64,  64, 64,  4, 5, 6 },
    { xcat + 64 * NPTS,    (long)512 * NPTS, 64,  128, 128, 7, 8, 9 },
    { xcat + 128 * NPTS,   (long)512 * NPTS, 128, 256, 256, 10, 11, 12 },
  };

  for (int L = 0; L < 4; ++L) {
    Layer& ly = layers[L];
    int P2 = 2 * ly.O;
    const float* W = (const float*)d_in[ly.wi];
    const float* g = (const float*)d_in[ly.gi];
    const float* bv = (const float*)d_in[ly.bi];

    int wtot = 2 * ly.O * ly.C;
    prep_w_kernel<<<(wtot + 255) / 256, 256, 0, stream>>>(W, g, wp, ly.O, ly.C);
    xx_kernel<<<dim3(NPTS / 256, BATCH), 256, 0, stream>>>(ly.x, xxb, ly.C, ly.bstride);
    dim3 sg(NPTS / 64, KSPLIT, BATCH);
    if (ly.C == 3) {
      knn_scan<3><<<sg, 256, 0, stream>>>(ly.x, xxb, knnD, knnI, ly.bstride);
    } else if (ly.C == 64) {
      knn_scan<64><<<sg, 256, 0, stream>>>(ly.x, xxb, knnD, knnI, ly.bstride);
    } else {
      knn_scan<128><<<sg, 256, 0, stream>>>(ly.x, xxb, knnD, knnI, ly.bstride);
    }
    knn_merge<<<(BATCH * NPTS) / 256, 256, 0, stream>>>(knnD, knnI, idxb);
    gemm_vsus_kernel<<<dim3(NPTS / 64, P2 / 64, BATCH), 256, 0, stream>>>(
        ly.x, wp, vsus, ly.C, P2, ly.bstride);
    gather_max_kernel<<<dim3(NPTS / 32, BATCH), 256, 0, stream>>>(
        vsus, idxb, bv, xcat, ly.O, ly.cho);
  }

  prep_mlpw_kernel<<<dim3(16, 32), 256, 0, stream>>>(
      (const float*)d_in[13], (const float*)d_in[14], wmlp);
  mlp_kernel<<<dim3(16, 8, BATCH), 256, 0, stream>>>(
      xcat, wmlp, (const float*)d_in[15], pbuf);
  mlp_reduce_kernel<<<32, 256, 0, stream>>>(pbuf, feat);

  fc_kernel<<<(BATCH * 512 * 64) / 256, 256, 0, stream>>>(
      feat, (const float*)d_in[16], (const float*)d_in[17],
      (const float*)d_in[18], (const float*)d_in[19], h1, BATCH, 512, 2048, 1);
  fc_kernel<<<(BATCH * 256 * 64) / 256, 256, 0, stream>>>(
      h1, (const float*)d_in[20], (const float*)d_in[21],
      (const float*)d_in[22], (const float*)d_in[23], h2, BATCH, 256, 512, 1);
  fc_kernel<<<(BATCH * 40 * 64) / 256, 256, 0, stream>>>(
      h2, (const float*)d_in[24], (const float*)d_in[25],
      nullptr, nullptr, (float*)d_out, BATCH, 40, 256, 0);
}

// Round 5
// 1462.312 us; speedup vs baseline: 4.3497x; 1.2908x over previous
//
#include <hip/hip_runtime.h>

#define NPTS 2048
#define BATCH 8
#define KNN 20
#define KSPLIT 4

typedef short short8v __attribute__((ext_vector_type(8)));
typedef float f32x4 __attribute__((ext_vector_type(4)));

__device__ __forceinline__ float leaky(float y) { return fmaxf(y, 0.2f * y); }

__device__ __forceinline__ short f2bf(float f) {
  unsigned u = __float_as_uint(f);
  unsigned r = (u + 0x7fffu + ((u >> 16) & 1u)) >> 16;
  return (short)r;
}
__device__ __forceinline__ float bf2f(short h) {
  return __uint_as_float(((unsigned)(unsigned short)h) << 16);
}

// ---------------- prep: Wp[2O][C] = [a*W1 ; a*(W2-W1)] ----------------
__global__ void prep_w_kernel(const float* __restrict__ W, const float* __restrict__ g,
                              float* __restrict__ Wp, int O, int C) {
  int t = blockIdx.x * 256 + threadIdx.x;
  if (t >= 2 * O * C) return;
  int row = t / C, c = t - row * C;
  float inv = rsqrtf(1.0f + 1e-5f);
  if (row < O) {
    Wp[t] = g[row] * inv * W[row * 2 * C + c];
  } else {
    int o = row - O;
    Wp[t] = g[o] * inv * (W[o * 2 * C + C + c] - W[o * 2 * C + c]);
  }
}

// prep mlp weight: transpose to k-major, fold bn scale. Wt[k][o], k<512, o<1024
__global__ void prep_mlpw_kernel(const float* __restrict__ W, const float* __restrict__ g,
                                 float* __restrict__ Wt) {
  __shared__ float tile[32][33];
  int k0 = blockIdx.x * 32;
  int o0 = blockIdx.y * 32;
  int tx = threadIdx.x & 31, tyq = threadIdx.x >> 5;
  for (int r = tyq; r < 32; r += 8)
    tile[r][tx] = W[(o0 + r) * 512 + k0 + tx];
  __syncthreads();
  float inv = rsqrtf(1.0f + 1e-5f);
  for (int r = tyq; r < 32; r += 8) {
    int k = k0 + r, o = o0 + tx;
    Wt[k * 1024 + o] = g[o] * inv * tile[tx][r];
  }
}

// ---------------- xx[b][m] = sum_c x[c][m]^2 (exact fp32) ----------------
__global__ void xx_kernel(const float* __restrict__ x, float* __restrict__ xx,
                          int C, long bstride) {
  int b = blockIdx.y;
  int m = blockIdx.x * 256 + threadIdx.x;
  const float* xb = x + (long)b * bstride;
  float s = 0.f;
  for (int c = 0; c < C; ++c) { float v = xb[c * NPTS + m]; s += v * v; }
  xx[b * NPTS + m] = s;
}

// ---------------- split x into hi/lo bf16 fragment layout ----------------
// XF[(chunk*4+g)*2048 + n] quad of 8 bf16: j -> channel c = chunk*32 + g*4 + (j&3) + 16*(j>>2)
__global__ void split_kernel(const float* __restrict__ x, short* __restrict__ xfh,
                             short* __restrict__ xfl, int C, int NCHUNK, long bstride) {
  int b = blockIdx.y;
  int t = blockIdx.x * 256 + threadIdx.x;   // cg*2048 + n
  int cg = t >> 11, n = t & 2047;
  int chunk = cg >> 2, g = cg & 3;
  const float* xb = x + (long)b * bstride;
  short8v h8, l8;
  #pragma unroll
  for (int j = 0; j < 8; ++j) {
    int c = chunk * 32 + g * 4 + (j & 3) + 16 * (j >> 2);
    float v = (c < C) ? xb[c * NPTS + n] : 0.f;
    short h = f2bf(v);
    float lo = v - bf2f(h);
    h8[j] = h;
    l8[j] = f2bf(lo);
  }
  long q = (long)b * NCHUNK * 4 * 2048 + t;
  *reinterpret_cast<short8v*>(xfh + q * 8) = h8;
  *reinterpret_cast<short8v*>(xfl + q * 8) = l8;
}

// ---------------- knn scan: MFMA hi/lo d2 gemm + register top-20 ----------------
template <int NCHUNK>
__global__ __launch_bounds__(256) void knn_scan(const short* __restrict__ xfh,
                                                const short* __restrict__ xfl,
                                                const float* __restrict__ xx,
                                                float* __restrict__ pd,
                                                unsigned short* __restrict__ pi) {
  __shared__ __align__(16) float smem[8384];
  // quads: B double-buffer [2][8 segs][65 quads] = quads 0..1039; d2t floats at 4160..8319
  short8v* qsm = (short8v*)smem;
  float* d2t = smem + 4160;
  float* mrgD = smem;                                     // alias after main loop
  unsigned short* mrgI = (unsigned short*)(smem + 5376);  // alias

  int tid = threadIdx.x;
  int lane = tid & 63, wv = tid >> 6;
  int b = blockIdx.z;
  int sidx = blockIdx.y;
  int n0 = blockIdx.x * 64;
  const float* xxb = xx + b * NPTS;
  const short8v* xfh_b = (const short8v*)xfh + (long)b * NCHUNK * 4 * 2048;
  const short8v* xfl_b = (const short8v*)xfl + (long)b * NCHUNK * 4 * 2048;

  // A fragments in registers: rows n0 + wv*16 + (lane&15), all chunks, both halves
  short8v afh[NCHUNK], afl[NCHUNK];
  #pragma unroll
  for (int c = 0; c < NCHUNK; ++c) {
    long qi = ((long)(c * 4 + (lane >> 4))) * 2048 + n0 + wv * 16 + (lane & 15);
    afh[c] = xfh_b[qi];
    afl[c] = xfl_b[qi];
  }
  float xvr[4];
  #pragma unroll
  for (int r = 0; r < 4; ++r) xvr[r] = xxb[n0 + wv * 16 + (lane >> 4) * 4 + r];

  float ld[20]; int li[20];
  #pragma unroll
  for (int k = 0; k < 20; ++k) { ld[k] = 1e30f; li[k] = 0x7fffffff; }

  int row = tid & 63, part = tid >> 6;
  int mt0 = sidx * 8;

  // prefetch (mtl=0, c=0) B-stage quads into regs
  short8v pA, pB;
  {
    long qi = ((long)(0 * 4 + wv)) * 2048 + mt0 * 64 + lane;
    pA = xfh_b[qi];
    pB = xfl_b[qi];
  }
  int par = 0;

  for (int mtl = 0; mtl < 8; ++mtl) {
    int m0 = (mt0 + mtl) * 64;
    f32x4 acc[4];
    #pragma unroll
    for (int f = 0; f < 4; ++f) acc[f] = (f32x4){0.f, 0.f, 0.f, 0.f};

    #pragma unroll
    for (int c = 0; c < NCHUNK; ++c) {
      // write staged quads: seg g=wv (hi) and 4+wv (lo)
      qsm[par * 520 + wv * 65 + lane] = pA;
      qsm[par * 520 + (4 + wv) * 65 + lane] = pB;
      __syncthreads();
      // prefetch next (chunk, tile)
      int nm = mtl, nc = c + 1;
      if (nc == NCHUNK) { nc = 0; nm = mtl + 1; }
      if (nm < 8) {
        long qi = ((long)(nc * 4 + wv)) * 2048 + (mt0 + nm) * 64 + lane;
        pA = xfh_b[qi];
        pB = xfl_b[qi];
      }
      // MFMA: 4 m-frags x {hh, lh, hl, ll}
      #pragma unroll
      for (int f = 0; f < 4; ++f) {
        short8v bh = qsm[par * 520 + (lane >> 4) * 65 + f * 16 + (lane & 15)];
        short8v bl = qsm[par * 520 + (4 + (lane >> 4)) * 65 + f * 16 + (lane & 15)];
        acc[f] = __builtin_amdgcn_mfma_f32_16x16x32_bf16(afh[c], bh, acc[f], 0, 0, 0);
        acc[f] = __builtin_amdgcn_mfma_f32_16x16x32_bf16(afl[c], bh, acc[f], 0, 0, 0);
        acc[f] = __builtin_amdgcn_mfma_f32_16x16x32_bf16(afh[c], bl, acc[f], 0, 0, 0);
        acc[f] = __builtin_amdgcn_mfma_f32_16x16x32_bf16(afl[c], bl, acc[f], 0, 0, 0);
      }
      par ^= 1;
    }

    // d2 tile: row = wv*16 + (lane>>4)*4 + r, col = f*16 + (lane&15)
    float xxm[4];
    #pragma unroll
    for (int f = 0; f < 4; ++f) xxm[f] = xxb[m0 + f * 16 + (lane & 15)];
    #pragma unroll
    for (int f = 0; f < 4; ++f) {
      int col = f * 16 + (lane & 15);
      #pragma unroll
      for (int r = 0; r < 4; ++r) {
        int rw = wv * 16 + (lane >> 4) * 4 + r;
        d2t[rw * 65 + col] = xvr[r] + xxm[f] - 2.f * acc[f][r];
      }
    }
    __syncthreads();

    // scan: all 256 lanes, row = tid&63, m-slice = part*16..+16
    #pragma unroll 4
    for (int j = 0; j < 16; ++j) {
      float v = d2t[row * 65 + part * 16 + j];
      if (v < ld[19]) {
        int m = m0 + part * 16 + j;
        #pragma unroll
        for (int k = 19; k >= 1; --k) {
          bool a = v < ld[k];
          bool s = v < ld[k - 1];
          float nd = a ? (s ? ld[k - 1] : v) : ld[k];
          int   ni = a ? (s ? li[k - 1] : m) : li[k];
          ld[k] = nd; li[k] = ni;
        }
        bool a0 = v < ld[0];
        li[0] = a0 ? m : li[0];
        ld[0] = a0 ? v : ld[0];
      }
    }
  }
  __syncthreads();   // all scans done before aliasing smem with merge lists

  #pragma unroll
  for (int k = 0; k < 20; ++k) {
    mrgD[(part * 64 + row) * 21 + k] = ld[k];
    mrgI[(part * 64 + row) * 21 + k] = (unsigned short)li[k];
  }
  __syncthreads();

  if (tid < 64) {
    int h0 = 0, h1 = 0, h2 = 0, h3 = 0;
    long obase = ((long)((b * KSPLIT + sidx) * NPTS) + n0 + tid) * KNN;
    for (int k = 0; k < KNN; ++k) {
      float v0 = mrgD[(0 * 64 + tid) * 21 + h0]; int i0 = mrgI[(0 * 64 + tid) * 21 + h0];
      float v1 = mrgD[(1 * 64 + tid) * 21 + h1]; int i1 = mrgI[(1 * 64 + tid) * 21 + h1];
      float v2 = mrgD[(2 * 64 + tid) * 21 + h2]; int i2 = mrgI[(2 * 64 + tid) * 21 + h2];
      float v3 = mrgD[(3 * 64 + tid) * 21 + h3]; int i3 = mrgI[(3 * 64 + tid) * 21 + h3];
      float bv = v0; int bi = i0; int bp = 0;
      if (v1 < bv || (v1 == bv && i1 < bi)) { bv = v1; bi = i1; bp = 1; }
      if (v2 < bv || (v2 == bv && i2 < bi)) { bv = v2; bi = i2; bp = 2; }
      if (v3 < bv || (v3 == bv && i3 < bi)) { bv = v3; bi = i3; bp = 3; }
      pd[obase + k] = bv;
      pi[obase + k] = (unsigned short)bi;
      h0 += (bp == 0); h1 += (bp == 1); h2 += (bp == 2); h3 += (bp == 3);
    }
  }
}

// ---------------- knn merge ----------------
__global__ void knn_merge(const float* __restrict__ pd, const unsigned short* __restrict__ pi,
                          int* __restrict__ idxout) {
  int t = blockIdx.x * 256 + threadIdx.x;
  int b = t >> 11, n = t & 2047;
  long base[KSPLIT]; int h[KSPLIT];
  #pragma unroll
  for (int s = 0; s < KSPLIT; ++s) {
    base[s] = ((long)((b * KSPLIT + s) * NPTS) + n) * KNN;
    h[s] = 0;
  }
  int* op = idxout + (long)t * KNN;
  for (int k = 0; k < KNN; ++k) {
    float bv = 1e38f; int bi = 0x7fffffff; int bs = 0;
    #pragma unroll
    for (int s = 0; s < KSPLIT; ++s) {
      float v = pd[base[s] + h[s]];
      int i = pi[base[s] + h[s]];
      if (v < bv || (v == bv && i < bi)) { bv = v; bi = i; bs = s; }
    }
    op[k] = bi;
    #pragma unroll
    for (int s = 0; s < KSPLIT; ++s) h[s] += (bs == s);
  }
}

// ---------------- vsus[b][n][p] = sum_c Wp[p][c] * x[c][n] ----------------
__global__ __launch_bounds__(256) void gemm_vsus_kernel(const float* __restrict__ x,
                                                        const float* __restrict__ Wp,
                                                        float* __restrict__ out,
                                                        int C, int P2, long bstride) {
  __shared__ float xs[32 * 65];
  __shared__ float wsd[32 * 65];
  int tid = threadIdx.x;
  int b = blockIdx.z;
  int n0 = blockIdx.x * 64;
  int p0 = blockIdx.y * 64;
  const float* xb = x + (long)b * bstride;
  float acc[4][4];
  #pragma unroll
  for (int r = 0; r < 4; ++r)
    #pragma unroll
    for (int m = 0; m < 4; ++m) acc[r][m] = 0.f;
  int ti = tid >> 4, tj = tid & 15;

  for (int k0 = 0; k0 < C; k0 += 32) {
    int kcnt = min(32, C - k0);
    __syncthreads();
    for (int i = tid; i < kcnt * 64; i += 256) {
      int kc = i >> 6, j = i & 63;
      xs[kc * 65 + j] = xb[(k0 + kc) * NPTS + n0 + j];
    }
    for (int i = tid; i < kcnt * 64; i += 256) {
      int kc = i % kcnt, p = i / kcnt;
      wsd[kc * 65 + p] = Wp[(p0 + p) * C + k0 + kc];
    }
    __syncthreads();
    for (int kc = 0; kc < kcnt; ++kc) {
      float av[4], bv[4];
      #pragma unroll
      for (int r = 0; r < 4; ++r) av[r] = xs[kc * 65 + ti * 4 + r];
      #pragma unroll
      for (int m = 0; m < 4; ++m) bv[m] = wsd[kc * 65 + tj * 4 + m];
      #pragma unroll
      for (int r = 0; r < 4; ++r)
        #pragma unroll
        for (int m = 0; m < 4; ++m) acc[r][m] += av[r] * bv[m];
    }
  }
  #pragma unroll
  for (int r = 0; r < 4; ++r) {
    int n = n0 + ti * 4 + r;
    float4 v = make_float4(acc[r][0], acc[r][1], acc[r][2], acc[r][3]);
    *reinterpret_cast<float4*>(out + (long)(b * NPTS + n) * P2 + p0 + tj * 4) = v;
  }
}

// ---------------- gather + max_k + leaky -> xcat channel block ----------------
__global__ __launch_bounds__(256) void gather_max_kernel(const float* __restrict__ vsus,
                                                         const int* __restrict__ idxin,
                                                         const float* __restrict__ bias,
                                                         float* __restrict__ xcat,
                                                         int O, int cho) {
  __shared__ int idxs[32 * KNN];
  __shared__ float ot[256 * 33];
  int tid = threadIdx.x;
  int b = blockIdx.y;
  int n0 = blockIdx.x * 32;
  int P2 = 2 * O;
  for (int i = tid; i < 32 * KNN; i += 256) idxs[i] = idxin[(b * NPTS + n0) * KNN + i];
  __syncthreads();
  int G = 256 / O;
  int o = tid % O;
  int ns = tid / O;
  float bo = bias[o];
  const float* vb = vsus + (long)b * NPTS * P2;
  for (int step = 0; step < 32 / G; ++step) {
    int nn = step * G + ns;
    float mx = -1e30f;
    for (int k = 0; k < KNN; ++k) {
      int j = idxs[nn * KNN + k];
      mx = fmaxf(mx, vb[j * P2 + o]);
    }
    float us = vb[(n0 + nn) * P2 + O + o] + bo;
    ot[o * 33 + nn] = leaky(mx + us);
  }
  __syncthreads();
  float* ob = xcat + ((long)b * 512 + cho) * NPTS + n0;
  for (int i = tid; i < O * 32; i += 256) {
    int oo = i >> 5, nn = i & 31;
    ob[oo * NPTS + nn] = ot[oo * 33 + nn];
  }
}

// ---------------- mlp: 128x128 tile, 8x8/thread, fused max/sum partials ----------------
__global__ __launch_bounds__(256) void mlp_kernel(const float* __restrict__ xcat,
                                                  const float* __restrict__ Wt,
                                                  const float* __restrict__ bvec,
                                                  float* __restrict__ pbuf) {
  __shared__ float As[32][132];
  __shared__ float Bs[32][132];
  int tid = threadIdx.x;
  int b = blockIdx.z;
  int ob = blockIdx.y;
  int nt = blockIdx.x;
  int o0 = ob * 128, n0 = nt * 128;
  const float* xb = xcat + (long)b * 512 * NPTS;
  int ty = tid >> 4, tx = tid & 15;

  float acc[2][4][2][4];
  #pragma unroll
  for (int q = 0; q < 2; ++q)
    #pragma unroll
    for (int j = 0; j < 4; ++j)
      #pragma unroll
      for (int p = 0; p < 2; ++p)
        #pragma unroll
        for (int i = 0; i < 4; ++i) acc[q][j][p][i] = 0.f;

  for (int k0 = 0; k0 < 512; k0 += 32) {
    __syncthreads();
    #pragma unroll
    for (int s = 0; s < 4; ++s) {
      int f4 = s * 256 + tid;
      int row = f4 >> 5, c4 = f4 & 31;
      *reinterpret_cast<float4*>(&As[row][c4 * 4]) =
          *reinterpret_cast<const float4*>(&Wt[(long)(k0 + row) * 1024 + o0 + c4 * 4]);
      *reinterpret_cast<float4*>(&Bs[row][c4 * 4]) =
          *reinterpret_cast<const float4*>(&xb[(long)(k0 + row) * NPTS + n0 + c4 * 4]);
    }
    __syncthreads();
    #pragma unroll 8
    for (int kc = 0; kc < 32; ++kc) {
      float av[2][4], bv[2][4];
      *reinterpret_cast<float4*>(av[0]) = *reinterpret_cast<const float4*>(&As[kc][ty * 4]);
      *reinterpret_cast<float4*>(av[1]) = *reinterpret_cast<const float4*>(&As[kc][64 + ty * 4]);
      *reinterpret_cast<float4*>(bv[0]) = *reinterpret_cast<const float4*>(&Bs[kc][tx * 4]);
      *reinterpret_cast<float4*>(bv[1]) = *reinterpret_cast<const float4*>(&Bs[kc][64 + tx * 4]);
      #pragma unroll
      for (int q = 0; q < 2; ++q)
        #pragma unroll
        for (int j = 0; j < 4; ++j)
          #pragma unroll
          for (int p = 0; p < 2; ++p)
            #pragma unroll
            for (int i = 0; i < 4; ++i) acc[q][j][p][i] += av[q][j] * bv[p][i];
    }
  }

  float rmax[2][4], rsum[2][4];
  #pragma unroll
  for (int q = 0; q < 2; ++q)
    #pragma unroll
    for (int j = 0; j < 4; ++j) {
      float bb = bvec[o0 + q * 64 + ty * 4 + j];
      float mx = -1e30f, sm = 0.f;
      #pragma unroll
      for (int p = 0; p < 2; ++p)
        #pragma unroll
        for (int i = 0; i < 4; ++i) {
          float y = leaky(acc[q][j][p][i] + bb);
          mx = fmaxf(mx, y);
          sm += y;
        }
      rmax[q][j] = mx;
      rsum[q][j] = sm;
    }
  #pragma unroll
  for (int off = 8; off; off >>= 1) {
    #pragma unroll
    for (int q = 0; q < 2; ++q)
      #pragma unroll
      for (int j = 0; j < 4; ++j) {
        rmax[q][j] = fmaxf(rmax[q][j], __shfl_xor(rmax[q][j], off));
        rsum[q][j] += __shfl_xor(rsum[q][j], off);
      }
  }
  if (tx == 0) {
    float* pb = pbuf + (((long)(b * 8 + ob) * 16 + nt) * 2) * 128;
    #pragma unroll
    for (int q = 0; q < 2; ++q)
      #pragma unroll
      for (int j = 0; j < 4; ++j) {
        int ol = q * 64 + ty * 4 + j;
        pb[ol] = rmax[q][j];
        pb[128 + ol] = rsum[q][j];
      }
  }
}

__global__ void mlp_reduce_kernel(const float* __restrict__ pbuf, float* __restrict__ feat) {
  int t = blockIdx.x * 256 + threadIdx.x;   // 8192
  int b = t >> 10, o = t & 1023;
  int ob = o >> 7, ol = o & 127;
  float mx = -1e30f, s = 0.f;
  for (int nt = 0; nt < 16; ++nt) {
    const float* pb = pbuf + (((long)(b * 8 + ob) * 16 + nt) * 2) * 128;
    mx = fmaxf(mx, pb[ol]);
    s += pb[128 + ol];
  }
  feat[b * 2048 + o] = mx;
  feat[b * 2048 + 1024 + o] = s * (1.f / 2048.f);
}

// ---------------- fc layers: one wave per output ----------------
__global__ void fc_kernel(const float* __restrict__ X, const float* __restrict__ W,
                          const float* __restrict__ bias, const float* __restrict__ g,
                          const float* __restrict__ bb, float* __restrict__ out,
                          int B, int O, int Kdim, int hasAct) {
  int gt = blockIdx.x * 256 + threadIdx.x;
  int wid = gt >> 6;
  int lane = threadIdx.x & 63;
  if (wid >= B * O) return;
  int b = wid / O, o = wid - b * O;
  const float* xr = X + (long)b * Kdim;
  const float* wr = W + (long)o * Kdim;
  float acc = 0.f;
  for (int c = lane; c < Kdim; c += 64) acc += xr[c] * wr[c];
  for (int off = 32; off; off >>= 1) acc += __shfl_down(acc, off);
  if (lane == 0) {
    float h = acc + bias[o];
    if (hasAct) {
      float a = g[o] * rsqrtf(1.0f + 1e-5f);
      h = a * h + bb[o];
      h = fmaxf(h, 0.2f * h);
    }
    out[b * O + o] = h;
  }
}

// ---------------- launch ----------------
extern "C" void kernel_launch(void* const* d_in, const int* in_sizes, int n_in,
                              void* d_out, int out_size, void* d_ws, size_t ws_size,
                              hipStream_t stream) {
  const float* points = (const float*)d_in[0];
  char* ws = (char*)d_ws;

  const size_t XCAT = 0;                         // [8][512][2048] f
  const size_t VSUS = 33554432;                  // [8][2048][512] f (aliased: knn partials, XF, pbuf)
  const size_t IDXB = 67108864;                  // [8][2048][20] i
  const size_t XXB  = 68419584;                  // [8][2048] f
  const size_t WP   = 68485120;                  // [512][128] f
  const size_t WMLP = 68747264;                  // [512][1024] f (k-major)
  const size_t FEAT = 71106560;                  // [8][2048] f
  const size_t H1   = 71172096;                  // [8][512] f
  const size_t H2   = 71188480;                  // [8][256] f

  float* xcat = (float*)(ws + XCAT);
  float* vsus = (float*)(ws + VSUS);
  int*   idxb = (int*)(ws + IDXB);
  float* xxb  = (float*)(ws + XXB);
  float* wp   = (float*)(ws + WP);
  float* wmlp = (float*)(ws + WMLP);
  float* feat = (float*)(ws + FEAT);
  float* h1   = (float*)(ws + H1);
  float* h2   = (float*)(ws + H2);

  // aliased into the vsus region (dead until gemm_vsus / after gather)
  float* knnD = (float*)(ws + VSUS);                              // 5.24 MB
  unsigned short* knnI = (unsigned short*)(ws + VSUS + 5242880);  // 2.62 MB
  short* xfh = (short*)(ws + VSUS + 8388608);                     // 4 MB max
  short* xfl = (short*)(ws + VSUS + 8388608 + 4194304);           // 4 MB max
  float* pbuf = (float*)(ws + VSUS);                              // 1 MB, after vsus dead

  struct Layer { const float* x; long bstride; int C, O, cho, wi, gi, bi; };
  Layer layers[4] = {
    { points,              (long)3 * NPTS,   3,   64, 0,   1, 2, 3 },
    { xcat,                (long)512 * NPTS, 64,  64, 64,  4, 5, 6 },
    { xcat + 64 * NPTS,    (long)512 * NPTS, 64,  128, 128, 7, 8, 9 },
    { xcat + 128 * NPTS,   (long)512 * NPTS, 128, 256, 256, 10, 11, 12 },
  };

  for (int L = 0; L < 4; ++L) {
    Layer& ly = layers[L];
    int P2 = 2 * ly.O;
    const float* W = (const float*)d_in[ly.wi];
    const float* g = (const float*)d_in[ly.gi];
    const float* bv = (const float*)d_in[ly.bi];
    int NCHUNK = (ly.C + 31) / 32;

    int wtot = 2 * ly.O * ly.C;
    prep_w_kernel<<<(wtot + 255) / 256, 256, 0, stream>>>(W, g, wp, ly.O, ly.C);
    xx_kernel<<<dim3(NPTS / 256, BATCH), 256, 0, stream>>>(ly.x, xxb, ly.C, ly.bstride);
    split_kernel<<<dim3(NCHUNK * 32, BATCH), 256, 0, stream>>>(
        ly.x, xfh, xfl, ly.C, NCHUNK, ly.bstride);
    dim3 sg(NPTS / 64, KSPLIT, BATCH);
    if (NCHUNK == 1) {
      knn_scan<1><<<sg, 256, 0, stream>>>(xfh, xfl, xxb, knnD, knnI);
    } else if (NCHUNK == 2) {
      knn_scan<2><<<sg, 256, 0, stream>>>(xfh, xfl, xxb, knnD, knnI);
    } else {
      knn_scan<4><<<sg, 256, 0, stream>>>(xfh, xfl, xxb, knnD, knnI);
    }
    knn_merge<<<(BATCH * NPTS) / 256, 256, 0, stream>>>(knnD, knnI, idxb);
    gemm_vsus_kernel<<<dim3(NPTS / 64, P2 / 64, BATCH), 256, 0, stream>>>(
        ly.x, wp, vsus, ly.C, P2, ly.bstride);
    gather_max_kernel<<<dim3(NPTS / 32, BATCH), 256, 0, stream>>>(
        vsus, idxb, bv, xcat, ly.O, ly.cho);
  }

  prep_mlpw_kernel<<<dim3(16, 32), 256, 0, stream>>>(
      (const float*)d_in[13], (const float*)d_in[14], wmlp);
  mlp_kernel<<<dim3(16, 8, BATCH), 256, 0, stream>>>(
      xcat, wmlp, (const float*)d_in[15], pbuf);
  mlp_reduce_kernel<<<32, 256, 0, stream>>>(pbuf, feat);

  fc_kernel<<<(BATCH * 512 * 64) / 256, 256, 0, stream>>>(
      feat, (const float*)d_in[16], (const float*)d_in[17],
      (const float*)d_in[18], (const float*)d_in[19], h1, BATCH, 512, 2048, 1);
  fc_kernel<<<(BATCH * 256 * 64) / 256, 256, 0, stream>>>(
      h1, (const float*)d_in[20], (const float*)d_in[21],
      (const float*)d_in[22], (const float*)d_in[23], h2, BATCH, 256, 512, 1);
  fc_kernel<<<(BATCH * 40 * 64) / 256, 256, 0, stream>>>(
      h2, (const float*)d_in[24], (const float*)d_in[25],
      nullptr, nullptr, (float*)d_out, BATCH, 40, 256, 0);
}

// Round 6
// 1457.604 us; speedup vs baseline: 4.3638x; 1.0032x over previous
//
#include <hip/hip_runtime.h>

#define NPTS 2048
#define BATCH 8
#define KNN 20
#define KSPLIT 8

typedef short short8v __attribute__((ext_vector_type(8)));
typedef float f32x4 __attribute__((ext_vector_type(4)));

__device__ __forceinline__ float leaky(float y) { return fmaxf(y, 0.2f * y); }

__device__ __forceinline__ short f2bf(float f) {
  unsigned u = __float_as_uint(f);
  unsigned r = (u + 0x7fffu + ((u >> 16) & 1u)) >> 16;
  return (short)r;
}
__device__ __forceinline__ float bf2f(short h) {
  return __uint_as_float(((unsigned)(unsigned short)h) << 16);
}

// ---------------- prep: Wp[2O][C] = [a*W1 ; a*(W2-W1)] ----------------
__global__ void prep_w_kernel(const float* __restrict__ W, const float* __restrict__ g,
                              float* __restrict__ Wp, int O, int C) {
  int t = blockIdx.x * 256 + threadIdx.x;
  if (t >= 2 * O * C) return;
  int row = t / C, c = t - row * C;
  float inv = rsqrtf(1.0f + 1e-5f);
  if (row < O) {
    Wp[t] = g[row] * inv * W[row * 2 * C + c];
  } else {
    int o = row - O;
    Wp[t] = g[o] * inv * (W[o * 2 * C + C + c] - W[o * 2 * C + c]);
  }
}

// prep mlp weight: transpose to k-major, fold bn scale. Wt[k][o], k<512, o<1024
__global__ void prep_mlpw_kernel(const float* __restrict__ W, const float* __restrict__ g,
                                 float* __restrict__ Wt) {
  __shared__ float tile[32][33];
  int k0 = blockIdx.x * 32;
  int o0 = blockIdx.y * 32;
  int tx = threadIdx.x & 31, tyq = threadIdx.x >> 5;
  for (int r = tyq; r < 32; r += 8)
    tile[r][tx] = W[(o0 + r) * 512 + k0 + tx];
  __syncthreads();
  float inv = rsqrtf(1.0f + 1e-5f);
  for (int r = tyq; r < 32; r += 8) {
    int k = k0 + r, o = o0 + tx;
    Wt[k * 1024 + o] = g[o] * inv * tile[tx][r];
  }
}

// ---------------- xx[b][m] = sum_c x[c][m]^2 (exact fp32) ----------------
__global__ void xx_kernel(const float* __restrict__ x, float* __restrict__ xx,
                          int C, long bstride) {
  int b = blockIdx.y;
  int m = blockIdx.x * 256 + threadIdx.x;
  const float* xb = x + (long)b * bstride;
  float s = 0.f;
  for (int c = 0; c < C; ++c) { float v = xb[c * NPTS + m]; s += v * v; }
  xx[b * NPTS + m] = s;
}

// ---------------- split x into hi/lo bf16 fragment layout ----------------
// XF[(chunk*4+g)*2048 + n] quad of 8 bf16: j -> channel c = chunk*32 + g*4 + (j&3) + 16*(j>>2)
__global__ void split_kernel(const float* __restrict__ x, short* __restrict__ xfh,
                             short* __restrict__ xfl, int C, int NCHUNK, long bstride) {
  int b = blockIdx.y;
  int t = blockIdx.x * 256 + threadIdx.x;   // cg*2048 + n
  int cg = t >> 11, n = t & 2047;
  int chunk = cg >> 2, g = cg & 3;
  const float* xb = x + (long)b * bstride;
  short8v h8, l8;
  #pragma unroll
  for (int j = 0; j < 8; ++j) {
    int c = chunk * 32 + g * 4 + (j & 3) + 16 * (j >> 2);
    float v = (c < C) ? xb[c * NPTS + n] : 0.f;
    short h = f2bf(v);
    float lo = v - bf2f(h);
    h8[j] = h;
    l8[j] = f2bf(lo);
  }
  long q = (long)b * NCHUNK * 4 * 2048 + t;
  *reinterpret_cast<short8v*>(xfh + q * 8) = h8;
  *reinterpret_cast<short8v*>(xfl + q * 8) = l8;
}

// ---------------- knn scan: MFMA hi/lo d2 gemm + register top-20 ----------------
template <int NCHUNK>
__global__ __launch_bounds__(256) void knn_scan(const short* __restrict__ xfh,
                                                const short* __restrict__ xfl,
                                                const float* __restrict__ xx,
                                                float* __restrict__ pd,
                                                unsigned short* __restrict__ pi) {
  __shared__ __align__(16) float smem[8384];
  // quads: B double-buffer [2][8 segs][65 quads] = quads 0..1039; d2t floats at 4160..8319
  short8v* qsm = (short8v*)smem;
  float* d2t = smem + 4160;
  float* mrgD = smem;                                     // alias after main loop
  unsigned short* mrgI = (unsigned short*)(smem + 5376);  // alias

  int tid = threadIdx.x;
  int lane = tid & 63, wv = tid >> 6;
  int b = blockIdx.z;
  int sidx = blockIdx.y;
  int n0 = blockIdx.x * 64;
  const float* xxb = xx + b * NPTS;
  const short8v* xfh_b = (const short8v*)xfh + (long)b * NCHUNK * 4 * 2048;
  const short8v* xfl_b = (const short8v*)xfl + (long)b * NCHUNK * 4 * 2048;

  // A fragments in registers: rows n0 + wv*16 + (lane&15), all chunks, both halves
  short8v afh[NCHUNK], afl[NCHUNK];
  #pragma unroll
  for (int c = 0; c < NCHUNK; ++c) {
    long qi = ((long)(c * 4 + (lane >> 4))) * 2048 + n0 + wv * 16 + (lane & 15);
    afh[c] = xfh_b[qi];
    afl[c] = xfl_b[qi];
  }
  float xvr[4];
  #pragma unroll
  for (int r = 0; r < 4; ++r) xvr[r] = xxb[n0 + wv * 16 + (lane >> 4) * 4 + r];

  float ld[20]; int li[20];
  #pragma unroll
  for (int k = 0; k < 20; ++k) { ld[k] = 1e30f; li[k] = 0x7fffffff; }

  int row = tid & 63, part = tid >> 6;
  int mt0 = sidx * (32 / KSPLIT);

  // prefetch (mtl=0, c=0) B-stage quads into regs
  short8v pA, pB;
  {
    long qi = ((long)(0 * 4 + wv)) * 2048 + mt0 * 64 + lane;
    pA = xfh_b[qi];
    pB = xfl_b[qi];
  }
  int par = 0;

  for (int mtl = 0; mtl < 32 / KSPLIT; ++mtl) {
    int m0 = (mt0 + mtl) * 64;
    f32x4 acc[4];
    #pragma unroll
    for (int f = 0; f < 4; ++f) acc[f] = (f32x4){0.f, 0.f, 0.f, 0.f};

    #pragma unroll
    for (int c = 0; c < NCHUNK; ++c) {
      // write staged quads: seg g=wv (hi) and 4+wv (lo)
      qsm[par * 520 + wv * 65 + lane] = pA;
      qsm[par * 520 + (4 + wv) * 65 + lane] = pB;
      __syncthreads();
      // prefetch next (chunk, tile)
      int nm = mtl, nc = c + 1;
      if (nc == NCHUNK) { nc = 0; nm = mtl + 1; }
      if (nm < 32 / KSPLIT) {
        long qi = ((long)(nc * 4 + wv)) * 2048 + (mt0 + nm) * 64 + lane;
        pA = xfh_b[qi];
        pB = xfl_b[qi];
      }
      // MFMA: 4 m-frags x {hh, lh, hl, ll}
      #pragma unroll
      for (int f = 0; f < 4; ++f) {
        short8v bh = qsm[par * 520 + (lane >> 4) * 65 + f * 16 + (lane & 15)];
        short8v bl = qsm[par * 520 + (4 + (lane >> 4)) * 65 + f * 16 + (lane & 15)];
        acc[f] = __builtin_amdgcn_mfma_f32_16x16x32_bf16(afh[c], bh, acc[f], 0, 0, 0);
        acc[f] = __builtin_amdgcn_mfma_f32_16x16x32_bf16(afl[c], bh, acc[f], 0, 0, 0);
        acc[f] = __builtin_amdgcn_mfma_f32_16x16x32_bf16(afh[c], bl, acc[f], 0, 0, 0);
        acc[f] = __builtin_amdgcn_mfma_f32_16x16x32_bf16(afl[c], bl, acc[f], 0, 0, 0);
      }
      par ^= 1;
    }

    // d2 tile: row = wv*16 + (lane>>4)*4 + r, col = f*16 + (lane&15)
    float xxm[4];
    #pragma unroll
    for (int f = 0; f < 4; ++f) xxm[f] = xxb[m0 + f * 16 + (lane & 15)];
    #pragma unroll
    for (int f = 0; f < 4; ++f) {
      int col = f * 16 + (lane & 15);
      #pragma unroll
      for (int r = 0; r < 4; ++r) {
        int rw = wv * 16 + (lane >> 4) * 4 + r;
        d2t[rw * 65 + col] = xvr[r] + xxm[f] - 2.f * acc[f][r];
      }
    }
    __syncthreads();

    // scan: all 256 lanes, row = tid&63, m-slice = part*16..+16
    #pragma unroll 4
    for (int j = 0; j < 16; ++j) {
      float v = d2t[row * 65 + part * 16 + j];
      if (v < ld[19]) {
        int m = m0 + part * 16 + j;
        #pragma unroll
        for (int k = 19; k >= 1; --k) {
          bool a = v < ld[k];
          bool s = v < ld[k - 1];
          float nd = a ? (s ? ld[k - 1] : v) : ld[k];
          int   ni = a ? (s ? li[k - 1] : m) : li[k];
          ld[k] = nd; li[k] = ni;
        }
        bool a0 = v < ld[0];
        li[0] = a0 ? m : li[0];
        ld[0] = a0 ? v : ld[0];
      }
    }
    __syncthreads();
  }

  #pragma unroll
  for (int k = 0; k < 20; ++k) {
    mrgD[(part * 64 + row) * 21 + k] = ld[k];
    mrgI[(part * 64 + row) * 21 + k] = (unsigned short)li[k];
  }
  __syncthreads();

  if (tid < 64) {
    int h0 = 0, h1 = 0, h2 = 0, h3 = 0;
    long obase = ((long)((b * KSPLIT + sidx) * NPTS) + n0 + tid) * KNN;
    for (int k = 0; k < KNN; ++k) {
      float v0 = mrgD[(0 * 64 + tid) * 21 + h0]; int i0 = mrgI[(0 * 64 + tid) * 21 + h0];
      float v1 = mrgD[(1 * 64 + tid) * 21 + h1]; int i1 = mrgI[(1 * 64 + tid) * 21 + h1];
      float v2 = mrgD[(2 * 64 + tid) * 21 + h2]; int i2 = mrgI[(2 * 64 + tid) * 21 + h2];
      float v3 = mrgD[(3 * 64 + tid) * 21 + h3]; int i3 = mrgI[(3 * 64 + tid) * 21 + h3];
      float bv = v0; int bi = i0; int bp = 0;
      if (v1 < bv || (v1 == bv && i1 < bi)) { bv = v1; bi = i1; bp = 1; }
      if (v2 < bv || (v2 == bv && i2 < bi)) { bv = v2; bi = i2; bp = 2; }
      if (v3 < bv || (v3 == bv && i3 < bi)) { bv = v3; bi = i3; bp = 3; }
      pd[obase + k] = bv;
      pi[obase + k] = (unsigned short)bi;
      h0 += (bp == 0); h1 += (bp == 1); h2 += (bp == 2); h3 += (bp == 3);
    }
  }
}

// ---------------- knn merge: KSPLIT partial lists -> final top-20 indices ----------------
__global__ void knn_merge(const float* __restrict__ pd, const unsigned short* __restrict__ pi,
                          int* __restrict__ idxout) {
  int t = blockIdx.x * 256 + threadIdx.x;
  int b = t >> 11, n = t & 2047;
  long base[KSPLIT]; int h[KSPLIT];
  #pragma unroll
  for (int s = 0; s < KSPLIT; ++s) {
    base[s] = ((long)((b * KSPLIT + s) * NPTS) + n) * KNN;
    h[s] = 0;
  }
  int* op = idxout + (long)t * KNN;
  for (int k = 0; k < KNN; ++k) {
    float bv = 1e38f; int bi = 0x7fffffff; int bs = 0;
    #pragma unroll
    for (int s = 0; s < KSPLIT; ++s) {
      float v = pd[base[s] + h[s]];
      int i = pi[base[s] + h[s]];
      if (v < bv || (v == bv && i < bi)) { bv = v; bi = i; bs = s; }
    }
    op[k] = bi;
    #pragma unroll
    for (int s = 0; s < KSPLIT; ++s) h[s] += (bs == s);
  }
}

// ---------------- vsus[b][n][p] = sum_c Wp[p][c] * x[c][n] ----------------
__global__ __launch_bounds__(256) void gemm_vsus_kernel(const float* __restrict__ x,
                                                        const float* __restrict__ Wp,
                                                        float* __restrict__ out,
                                                        int C, int P2, long bstride) {
  __shared__ float xs[32 * 65];
  __shared__ float wsd[32 * 65];
  int tid = threadIdx.x;
  int b = blockIdx.z;
  int n0 = blockIdx.x * 64;
  int p0 = blockIdx.y * 64;
  const float* xb = x + (long)b * bstride;
  float acc[4][4];
  #pragma unroll
  for (int r = 0; r < 4; ++r)
    #pragma unroll
    for (int m = 0; m < 4; ++m) acc[r][m] = 0.f;
  int ti = tid >> 4, tj = tid & 15;

  for (int k0 = 0; k0 < C; k0 += 32) {
    int kcnt = min(32, C - k0);
    __syncthreads();
    for (int i = tid; i < kcnt * 64; i += 256) {
      int kc = i >> 6, j = i & 63;
      xs[kc * 65 + j] = xb[(k0 + kc) * NPTS + n0 + j];
    }
    for (int i = tid; i < kcnt * 64; i += 256) {
      int kc = i % kcnt, p = i / kcnt;
      wsd[kc * 65 + p] = Wp[(p0 + p) * C + k0 + kc];
    }
    __syncthreads();
    for (int kc = 0; kc < kcnt; ++kc) {
      float av[4], bv[4];
      #pragma unroll
      for (int r = 0; r < 4; ++r) av[r] = xs[kc * 65 + ti * 4 + r];
      #pragma unroll
      for (int m = 0; m < 4; ++m) bv[m] = wsd[kc * 65 + tj * 4 + m];
      #pragma unroll
      for (int r = 0; r < 4; ++r)
        #pragma unroll
        for (int m = 0; m < 4; ++m) acc[r][m] += av[r] * bv[m];
    }
  }
  #pragma unroll
  for (int r = 0; r < 4; ++r) {
    int n = n0 + ti * 4 + r;
    float4 v = make_float4(acc[r][0], acc[r][1], acc[r][2], acc[r][3]);
    *reinterpret_cast<float4*>(out + (long)(b * NPTS + n) * P2 + p0 + tj * 4) = v;
  }
}

// ---------------- gather + max_k + leaky -> xcat channel block ----------------
__global__ __launch_bounds__(256) void gather_max_kernel(const float* __restrict__ vsus,
                                                         const int* __restrict__ idxin,
                                                         const float* __restrict__ bias,
                                                         float* __restrict__ xcat,
                                                         int O, int cho) {
  __shared__ int idxs[32 * KNN];
  __shared__ float ot[256 * 33];
  int tid = threadIdx.x;
  int b = blockIdx.y;
  int n0 = blockIdx.x * 32;
  int P2 = 2 * O;
  for (int i = tid; i < 32 * KNN; i += 256) idxs[i] = idxin[(b * NPTS + n0) * KNN + i];
  __syncthreads();
  int G = 256 / O;
  int o = tid % O;
  int ns = tid / O;
  float bo = bias[o];
  const float* vb = vsus + (long)b * NPTS * P2;
  for (int step = 0; step < 32 / G; ++step) {
    int nn = step * G + ns;
    float mx = -1e30f;
    for (int k = 0; k < KNN; ++k) {
      int j = idxs[nn * KNN + k];
      mx = fmaxf(mx, vb[j * P2 + o]);
    }
    float us = vb[(n0 + nn) * P2 + O + o] + bo;
    ot[o * 33 + nn] = leaky(mx + us);
  }
  __syncthreads();
  float* ob = xcat + ((long)b * 512 + cho) * NPTS + n0;
  for (int i = tid; i < O * 32; i += 256) {
    int oo = i >> 5, nn = i & 31;
    ob[oo * NPTS + nn] = ot[oo * 33 + nn];
  }
}

// ---------------- mlp: 128x128 tile, 8x8/thread, fused max/sum partials ----------------
__global__ __launch_bounds__(256) void mlp_kernel(const float* __restrict__ xcat,
                                                  const float* __restrict__ Wt,
                                                  const float* __restrict__ bvec,
                                                  float* __restrict__ pbuf) {
  __shared__ float As[32][132];
  __shared__ float Bs[32][132];
  int tid = threadIdx.x;
  int b = blockIdx.z;
  int ob = blockIdx.y;
  int nt = blockIdx.x;
  int o0 = ob * 128, n0 = nt * 128;
  const float* xb = xcat + (long)b * 512 * NPTS;
  int ty = tid >> 4, tx = tid & 15;

  float acc[2][4][2][4];
  #pragma unroll
  for (int q = 0; q < 2; ++q)
    #pragma unroll
    for (int j = 0; j < 4; ++j)
      #pragma unroll
      for (int p = 0; p < 2; ++p)
        #pragma unroll
        for (int i = 0; i < 4; ++i) acc[q][j][p][i] = 0.f;

  for (int k0 = 0; k0 < 512; k0 += 32) {
    __syncthreads();
    #pragma unroll
    for (int s = 0; s < 4; ++s) {
      int f4 = s * 256 + tid;
      int row = f4 >> 5, c4 = f4 & 31;
      *reinterpret_cast<float4*>(&As[row][c4 * 4]) =
          *reinterpret_cast<const float4*>(&Wt[(long)(k0 + row) * 1024 + o0 + c4 * 4]);
      *reinterpret_cast<float4*>(&Bs[row][c4 * 4]) =
          *reinterpret_cast<const float4*>(&xb[(long)(k0 + row) * NPTS + n0 + c4 * 4]);
    }
    __syncthreads();
    #pragma unroll 8
    for (int kc = 0; kc < 32; ++kc) {
      float av[2][4], bv[2][4];
      *reinterpret_cast<float4*>(av[0]) = *reinterpret_cast<const float4*>(&As[kc][ty * 4]);
      *reinterpret_cast<float4*>(av[1]) = *reinterpret_cast<const float4*>(&As[kc][64 + ty * 4]);
      *reinterpret_cast<float4*>(bv[0]) = *reinterpret_cast<const float4*>(&Bs[kc][tx * 4]);
      *reinterpret_cast<float4*>(bv[1]) = *reinterpret_cast<const float4*>(&Bs[kc][64 + tx * 4]);
      #pragma unroll
      for (int q = 0; q < 2; ++q)
        #pragma unroll
        for (int j = 0; j < 4; ++j)
          #pragma unroll
          for (int p = 0; p < 2; ++p)
            #pragma unroll
            for (int i = 0; i < 4; ++i) acc[q][j][p][i] += av[q][j] * bv[p][i];
    }
  }

  float rmax[2][4], rsum[2][4];
  #pragma unroll
  for (int q = 0; q < 2; ++q)
    #pragma unroll
    for (int j = 0; j < 4; ++j) {
      float bb = bvec[o0 + q * 64 + ty * 4 + j];
      float mx = -1e30f, sm = 0.f;
      #pragma unroll
      for (int p = 0; p < 2; ++p)
        #pragma unroll
        for (int i = 0; i < 4; ++i) {
          float y = leaky(acc[q][j][p][i] + bb);
          mx = fmaxf(mx, y);
          sm += y;
        }
      rmax[q][j] = mx;
      rsum[q][j] = sm;
    }
  #pragma unroll
  for (int off = 8; off; off >>= 1) {
    #pragma unroll
    for (int q = 0; q < 2; ++q)
      #pragma unroll
      for (int j = 0; j < 4; ++j) {
        rmax[q][j] = fmaxf(rmax[q][j], __shfl_xor(rmax[q][j], off));
        rsum[q][j] += __shfl_xor(rsum[q][j], off);
      }
  }
  if (tx == 0) {
    float* pb = pbuf + (((long)(b * 8 + ob) * 16 + nt) * 2) * 128;
    #pragma unroll
    for (int q = 0; q < 2; ++q)
      #pragma unroll
      for (int j = 0; j < 4; ++j) {
        int ol = q * 64 + ty * 4 + j;
        pb[ol] = rmax[q][j];
        pb[128 + ol] = rsum[q][j];
      }
  }
}

__global__ void mlp_reduce_kernel(const float* __restrict__ pbuf, float* __restrict__ feat) {
  int t = blockIdx.x * 256 + threadIdx.x;   // 8192
  int b = t >> 10, o = t & 1023;
  int ob = o >> 7, ol = o & 127;
  float mx = -1e30f, s = 0.f;
  for (int nt = 0; nt < 16; ++nt) {
    const float* pb = pbuf + (((long)(b * 8 + ob) * 16 + nt) * 2) * 128;
    mx = fmaxf(mx, pb[ol]);
    s += pb[128 + ol];
  }
  feat[b * 2048 + o] = mx;
  feat[b * 2048 + 1024 + o] = s * (1.f / 2048.f);
}

// ---------------- fc layers: one wave per output ----------------
__global__ void fc_kernel(const float* __restrict__ X, const float* __restrict__ W,
                          const float* __restrict__ bias, const float* __restrict__ g,
                          const float* __restrict__ bb, float* __restrict__ out,
                          int B, int O, int Kdim, int hasAct) {
  int gt = blockIdx.x * 256 + threadIdx.x;
  int wid = gt >> 6;
  int lane = threadIdx.x & 63;
  if (wid >= B * O) return;
  int b = wid / O, o = wid - b * O;
  const float* xr = X + (long)b * Kdim;
  const float* wr = W + (long)o * Kdim;
  float acc = 0.f;
  for (int c = lane; c < Kdim; c += 64) acc += xr[c] * wr[c];
  for (int off = 32; off; off >>= 1) acc += __shfl_down(acc, off);
  if (lane == 0) {
    float h = acc + bias[o];
    if (hasAct) {
      float a = g[o] * rsqrtf(1.0f + 1e-5f);
      h = a * h + bb[o];
      h = fmaxf(h, 0.2f * h);
    }
    out[b * O + o] = h;
  }
}

// ---------------- launch ----------------
extern "C" void kernel_launch(void* const* d_in, const int* in_sizes, int n_in,
                              void* d_out, int out_size, void* d_ws, size_t ws_size,
                              hipStream_t stream) {
  const float* points = (const float*)d_in[0];
  char* ws = (char*)d_ws;

  const size_t XCAT = 0;                         // [8][512][2048] f
  const size_t VSUS = 33554432;                  // [8][2048][512] f (aliased: knn partials, XF, pbuf)
  const size_t IDXB = 67108864;                  // [8][2048][20] i
  const size_t XXB  = 68419584;                  // [8][2048] f
  const size_t WP   = 68485120;                  // [512][128] f
  const size_t WMLP = 68747264;                  // [512][1024] f (k-major)
  const size_t FEAT = 71106560;                  // [8][2048] f
  const size_t H1   = 71172096;                  // [8][512] f
  const size_t H2   = 71188480;                  // [8][256] f

  float* xcat = (float*)(ws + XCAT);
  float* vsus = (float*)(ws + VSUS);
  int*   idxb = (int*)(ws + IDXB);
  float* xxb  = (float*)(ws + XXB);
  float* wp   = (float*)(ws + WP);
  float* wmlp = (float*)(ws + WMLP);
  float* feat = (float*)(ws + FEAT);
  float* h1   = (float*)(ws + H1);
  float* h2   = (float*)(ws + H2);

  // aliased into the vsus region (dead until gemm_vsus / after gather)
  // knnD: 8*16384*20*4 = 10.49 MB ; knnI: 5.24 MB ; xfh/xfl: 4 MB each
  float* knnD = (float*)(ws + VSUS);
  unsigned short* knnI = (unsigned short*)(ws + VSUS + 10485760);
  short* xfh = (short*)(ws + VSUS + 16777216);
  short* xfl = (short*)(ws + VSUS + 16777216 + 4194304);
  float* pbuf = (float*)(ws + VSUS);             // 1 MB, used after vsus dead

  struct Layer { const float* x; long bstride; int C, O, cho, wi, gi, bi; };
  Layer layers[4] = {
    { points,              (long)3 * NPTS,   3,   64, 0,   1, 2, 3 },
    { xcat,                (long)512 * NPTS, 64,  64, 64,  4, 5, 6 },
    { xcat + 64 * NPTS,    (long)512 * NPTS, 64,  128, 128, 7, 8, 9 },
    { xcat + 128 * NPTS,   (long)512 * NPTS, 128, 256, 256, 10, 11, 12 },
  };

  for (int L = 0; L < 4; ++L) {
    Layer& ly = layers[L];
    int P2 = 2 * ly.O;
    const float* W = (const float*)d_in[ly.wi];
    const float* g = (const float*)d_in[ly.gi];
    const float* bv = (const float*)d_in[ly.bi];
    int NCHUNK = (ly.C + 31) / 32;

    int wtot = 2 * ly.O * ly.C;
    prep_w_kernel<<<(wtot + 255) / 256, 256, 0, stream>>>(W, g, wp, ly.O, ly.C);
    xx_kernel<<<dim3(NPTS / 256, BATCH), 256, 0, stream>>>(ly.x, xxb, ly.C, ly.bstride);
    split_kernel<<<dim3(NCHUNK * 32, BATCH), 256, 0, stream>>>(
        ly.x, xfh, xfl, ly.C, NCHUNK, ly.bstride);
    dim3 sg(NPTS / 64, KSPLIT, BATCH);
    if (NCHUNK == 1) {
      knn_scan<1><<<sg, 256, 0, stream>>>(xfh, xfl, xxb, knnD, knnI);
    } else if (NCHUNK == 2) {
      knn_scan<2><<<sg, 256, 0, stream>>>(xfh, xfl, xxb, knnD, knnI);
    } else {
      knn_scan<4><<<sg, 256, 0, stream>>>(xfh, xfl, xxb, knnD, knnI);
    }
    knn_merge<<<(BATCH * NPTS) / 256, 256, 0, stream>>>(knnD, knnI, idxb);
    gemm_vsus_kernel<<<dim3(NPTS / 64, P2 / 64, BATCH), 256, 0, stream>>>(
        ly.x, wp, vsus, ly.C, P2, ly.bstride);
    gather_max_kernel<<<dim3(NPTS / 32, BATCH), 256, 0, stream>>>(
        vsus, idxb, bv, xcat, ly.O, ly.cho);
  }

  prep_mlpw_kernel<<<dim3(16, 32), 256, 0, stream>>>(
      (const float*)d_in[13], (const float*)d_in[14], wmlp);
  mlp_kernel<<<dim3(16, 8, BATCH), 256, 0, stream>>>(
      xcat, wmlp, (const float*)d_in[15], pbuf);
  mlp_reduce_kernel<<<32, 256, 0, stream>>>(pbuf, feat);

  fc_kernel<<<(BATCH * 512 * 64) / 256, 256, 0, stream>>>(
      feat, (const float*)d_in[16], (const float*)d_in[17],
      (const float*)d_in[18], (const float*)d_in[19], h1, BATCH, 512, 2048, 1);
  fc_kernel<<<(BATCH * 256 * 64) / 256, 256, 0, stream>>>(
      h1, (const float*)d_in[20], (const float*)d_in[21],
      (const float*)d_in[22], (const float*)d_in[23], h2, BATCH, 256, 512, 1);
  fc_kernel<<<(BATCH * 40 * 64) / 256, 256, 0, stream>>>(
      h2, (const float*)d_in[24], (const float*)d_in[25],
      nullptr, nullptr, (float*)d_out, BATCH, 40, 256, 0);
}

// Round 7
// 1077.079 us; speedup vs baseline: 5.9054x; 1.3533x over previous
//
#include <hip/hip_runtime.h>

#define NPTS 2048
#define BATCH 8
#define KNN 20
#define KSPLIT 4

typedef short short8v __attribute__((ext_vector_type(8)));
typedef float f32x4 __attribute__((ext_vector_type(4)));

__device__ __forceinline__ float leaky(float y) { return fmaxf(y, 0.2f * y); }

__device__ __forceinline__ short f2bf(float f) {
  unsigned u = __float_as_uint(f);
  unsigned r = (u + 0x7fffu + ((u >> 16) & 1u)) >> 16;
  return (short)r;
}
__device__ __forceinline__ float bf2f(short h) {
  return __uint_as_float(((unsigned)(unsigned short)h) << 16);
}

// ---------------- prep: Wp[2O][C] = [a*W1 ; a*(W2-W1)] ----------------
__global__ void prep_w_kernel(const float* __restrict__ W, const float* __restrict__ g,
                              float* __restrict__ Wp, int O, int C) {
  int t = blockIdx.x * 256 + threadIdx.x;
  if (t >= 2 * O * C) return;
  int row = t / C, c = t - row * C;
  float inv = rsqrtf(1.0f + 1e-5f);
  if (row < O) {
    Wp[t] = g[row] * inv * W[row * 2 * C + c];
  } else {
    int o = row - O;
    Wp[t] = g[o] * inv * (W[o * 2 * C + C + c] - W[o * 2 * C + c]);
  }
}

// prep mlp weight: transpose to k-major, fold bn scale. Wt[k][o], k<512, o<1024
__global__ void prep_mlpw_kernel(const float* __restrict__ W, const float* __restrict__ g,
                                 float* __restrict__ Wt) {
  __shared__ float tile[32][33];
  int k0 = blockIdx.x * 32;
  int o0 = blockIdx.y * 32;
  int tx = threadIdx.x & 31, tyq = threadIdx.x >> 5;
  for (int r = tyq; r < 32; r += 8)
    tile[r][tx] = W[(o0 + r) * 512 + k0 + tx];
  __syncthreads();
  float inv = rsqrtf(1.0f + 1e-5f);
  for (int r = tyq; r < 32; r += 8) {
    int k = k0 + r, o = o0 + tx;
    Wt[k * 1024 + o] = g[o] * inv * tile[tx][r];
  }
}

// ---------------- xx[b][m] = sum_c x[c][m]^2 (exact fp32) ----------------
__global__ void xx_kernel(const float* __restrict__ x, float* __restrict__ xx,
                          int C, long bstride) {
  int b = blockIdx.y;
  int m = blockIdx.x * 256 + threadIdx.x;
  const float* xb = x + (long)b * bstride;
  float s = 0.f;
  for (int c = 0; c < C; ++c) { float v = xb[c * NPTS + m]; s += v * v; }
  xx[b * NPTS + m] = s;
}

// ---------------- split x into hi/lo bf16 fragment layout ----------------
// XF[(chunk*4+g)*2048 + n] quad of 8 bf16: j -> channel c = chunk*32 + g*4 + (j&3) + 16*(j>>2)
__global__ void split_kernel(const float* __restrict__ x, short* __restrict__ xfh,
                             short* __restrict__ xfl, int C, int NCHUNK, long bstride) {
  int b = blockIdx.y;
  int t = blockIdx.x * 256 + threadIdx.x;   // cg*2048 + n
  int cg = t >> 11, n = t & 2047;
  int chunk = cg >> 2, g = cg & 3;
  const float* xb = x + (long)b * bstride;
  short8v h8, l8;
  #pragma unroll
  for (int j = 0; j < 8; ++j) {
    int c = chunk * 32 + g * 4 + (j & 3) + 16 * (j >> 2);
    float v = (c < C) ? xb[c * NPTS + n] : 0.f;
    short h = f2bf(v);
    float lo = v - bf2f(h);
    h8[j] = h;
    l8[j] = f2bf(lo);
  }
  long q = (long)b * NCHUNK * 4 * 2048 + t;
  *reinterpret_cast<short8v*>(xfh + q * 8) = h8;
  *reinterpret_cast<short8v*>(xfl + q * 8) = l8;
}

// ---------------- knn scan: MFMA hi/lo d2 gemm + register top-20 + in-wave merge ----------------
// lane mapping: wv = tid>>6, pt = tid&15, part = (tid>>4)&3
// thread scans row (wv*16+pt), cols part*16..+16 of each 64x64 d2 tile.
template <int NCHUNK>
__global__ __launch_bounds__(256, 5) void knn_scan(const short* __restrict__ xfh,
                                                   const short* __restrict__ xfl,
                                                   const float* __restrict__ xx,
                                                   float* __restrict__ pd,
                                                   unsigned short* __restrict__ pi) {
  __shared__ __align__(16) float smem[6432];
  short8v* qsm = (short8v*)smem;   // single buffer: [8 segs][65 quads] = 520 quads (8320 B)
  float* d2t = smem + 2080;        // [64][68] floats (17408 B)

  int tid = threadIdx.x;
  int lane = tid & 63, wv = tid >> 6;
  int pt = lane & 15;
  int part = (lane >> 4) & 3;
  int b = blockIdx.z;
  int sidx = blockIdx.y;
  int n0 = blockIdx.x * 64;
  const float* xxb = xx + b * NPTS;
  const short8v* xfh_b = (const short8v*)xfh + (long)b * NCHUNK * 4 * 2048;
  const short8v* xfl_b = (const short8v*)xfl + (long)b * NCHUNK * 4 * 2048;

  // A fragments in registers: rows n0 + wv*16 + (lane&15), all chunks, both halves
  short8v afh[NCHUNK], afl[NCHUNK];
  #pragma unroll
  for (int c = 0; c < NCHUNK; ++c) {
    long qi = ((long)(c * 4 + (lane >> 4))) * 2048 + n0 + wv * 16 + pt;
    afh[c] = xfh_b[qi];
    afl[c] = xfl_b[qi];
  }
  float xvr[4];
  #pragma unroll
  for (int r = 0; r < 4; ++r) xvr[r] = xxb[n0 + wv * 16 + (lane >> 4) * 4 + r];

  float ld[20]; int li[20];
  #pragma unroll
  for (int k = 0; k < 20; ++k) { ld[k] = 1e30f; li[k] = 0x7fffffff; }

  int mt0 = sidx * (32 / KSPLIT);

  // prefetch (mtl=0, c=0) B-stage quads into regs
  short8v pA, pB;
  {
    long qi = ((long)(0 * 4 + wv)) * 2048 + mt0 * 64 + lane;
    pA = xfh_b[qi];
    pB = xfl_b[qi];
  }

  for (int mtl = 0; mtl < 32 / KSPLIT; ++mtl) {
    int m0 = (mt0 + mtl) * 64;
    f32x4 acc[4];
    #pragma unroll
    for (int f = 0; f < 4; ++f) acc[f] = (f32x4){0.f, 0.f, 0.f, 0.f};

    #pragma unroll
    for (int c = 0; c < NCHUNK; ++c) {
      __syncthreads();   // previous chunk's MFMA reads / previous tile's scan done
      qsm[wv * 65 + lane] = pA;
      qsm[(4 + wv) * 65 + lane] = pB;
      __syncthreads();
      // prefetch next (chunk, tile)
      int nm = mtl, nc = c + 1;
      if (nc == NCHUNK) { nc = 0; nm = mtl + 1; }
      if (nm < 32 / KSPLIT) {
        long qi = ((long)(nc * 4 + wv)) * 2048 + (mt0 + nm) * 64 + lane;
        pA = xfh_b[qi];
        pB = xfl_b[qi];
      }
      // MFMA: 4 m-frags x {hh, lh, hl, ll}
      #pragma unroll
      for (int f = 0; f < 4; ++f) {
        short8v bh = qsm[(lane >> 4) * 65 + f * 16 + pt];
        short8v bl = qsm[(4 + (lane >> 4)) * 65 + f * 16 + pt];
        acc[f] = __builtin_amdgcn_mfma_f32_16x16x32_bf16(afh[c], bh, acc[f], 0, 0, 0);
        acc[f] = __builtin_amdgcn_mfma_f32_16x16x32_bf16(afl[c], bh, acc[f], 0, 0, 0);
        acc[f] = __builtin_amdgcn_mfma_f32_16x16x32_bf16(afh[c], bl, acc[f], 0, 0, 0);
        acc[f] = __builtin_amdgcn_mfma_f32_16x16x32_bf16(afl[c], bl, acc[f], 0, 0, 0);
      }
    }

    // d2 tile: row = wv*16 + (lane>>4)*4 + r, col = f*16 + pt
    float xxm[4];
    #pragma unroll
    for (int f = 0; f < 4; ++f) xxm[f] = xxb[m0 + f * 16 + pt];
    #pragma unroll
    for (int f = 0; f < 4; ++f) {
      int col = f * 16 + pt;
      #pragma unroll
      for (int r = 0; r < 4; ++r) {
        int rw = wv * 16 + (lane >> 4) * 4 + r;
        d2t[rw * 68 + col] = xvr[r] + xxm[f] - 2.f * acc[f][r];
      }
    }
    __syncthreads();

    // scan: thread owns row wv*16+pt, m-slice part*16..+16 (float4 reads)
    int srow = wv * 16 + pt;
    #pragma unroll
    for (int j4 = 0; j4 < 4; ++j4) {
      f32x4 vq = *reinterpret_cast<f32x4*>(&d2t[srow * 68 + part * 16 + j4 * 4]);
      #pragma unroll
      for (int e = 0; e < 4; ++e) {
        float v = vq[e];
        if (v < ld[19]) {
          int m = m0 + part * 16 + j4 * 4 + e;
          #pragma unroll
          for (int k = 19; k >= 1; --k) {
            bool a = v < ld[k];
            bool s = v < ld[k - 1];
            float nd = a ? (s ? ld[k - 1] : v) : ld[k];
            int   ni = a ? (s ? li[k - 1] : m) : li[k];
            ld[k] = nd; li[k] = ni;
          }
          bool a0 = v < ld[0];
          li[0] = a0 ? m : li[0];
          ld[0] = a0 ? v : ld[0];
        }
      }
    }
    // next tile's first __syncthreads() (inside chunk loop) protects d2t/qsm reuse
  }

  // ---- in-wave 4-way merge: group = lanes {pt, pt+16, pt+32, pt+48} ----
  long obase = ((long)((b * KSPLIT + sidx) * NPTS) + n0 + wv * 16 + pt) * KNN;
  float h = ld[0]; int hi = li[0];
  #pragma unroll
  for (int k = 0; k < KNN; ++k) {
    float v0 = __shfl(h, pt);        int i0 = __shfl(hi, pt);
    float v1 = __shfl(h, pt + 16);   int i1 = __shfl(hi, pt + 16);
    float v2 = __shfl(h, pt + 32);   int i2 = __shfl(hi, pt + 32);
    float v3 = __shfl(h, pt + 48);   int i3 = __shfl(hi, pt + 48);
    float bv = v0; int bi = i0; int bp = 0;
    if (v1 < bv || (v1 == bv && i1 < bi)) { bv = v1; bi = i1; bp = 1; }
    if (v2 < bv || (v2 == bv && i2 < bi)) { bv = v2; bi = i2; bp = 2; }
    if (v3 < bv || (v3 == bv && i3 < bi)) { bv = v3; bi = i3; bp = 3; }
    if (part == 0) {
      pd[obase + k] = bv;
      pi[obase + k] = (unsigned short)bi;
    }
    bool pop = (part == bp);
    #pragma unroll
    for (int i = 0; i < 19; ++i) {
      ld[i] = pop ? ld[i + 1] : ld[i];
      li[i] = pop ? li[i + 1] : li[i];
    }
    ld[19] = pop ? 1e30f : ld[19];
    li[19] = pop ? 0x7fffffff : li[19];
    h = ld[0]; hi = li[0];
  }
}

// ---------------- knn merge: KSPLIT partial lists -> final top-20 indices ----------------
__global__ void knn_merge(const float* __restrict__ pd, const unsigned short* __restrict__ pi,
                          int* __restrict__ idxout) {
  int t = blockIdx.x * 256 + threadIdx.x;
  int b = t >> 11, n = t & 2047;
  long base[KSPLIT]; int h[KSPLIT];
  #pragma unroll
  for (int s = 0; s < KSPLIT; ++s) {
    base[s] = ((long)((b * KSPLIT + s) * NPTS) + n) * KNN;
    h[s] = 0;
  }
  int* op = idxout + (long)t * KNN;
  for (int k = 0; k < KNN; ++k) {
    float bv = 1e38f; int bi = 0x7fffffff; int bs = 0;
    #pragma unroll
    for (int s = 0; s < KSPLIT; ++s) {
      float v = pd[base[s] + h[s]];
      int i = pi[base[s] + h[s]];
      if (v < bv || (v == bv && i < bi)) { bv = v; bi = i; bs = s; }
    }
    op[k] = bi;
    #pragma unroll
    for (int s = 0; s < KSPLIT; ++s) h[s] += (bs == s);
  }
}

// ---------------- vsus[b][n][p] = sum_c Wp[p][c] * x[c][n] ----------------
__global__ __launch_bounds__(256) void gemm_vsus_kernel(const float* __restrict__ x,
                                                        const float* __restrict__ Wp,
                                                        float* __restrict__ out,
                                                        int C, int P2, long bstride) {
  __shared__ float xs[32 * 65];
  __shared__ float wsd[32 * 65];
  int tid = threadIdx.x;
  int b = blockIdx.z;
  int n0 = blockIdx.x * 64;
  int p0 = blockIdx.y * 64;
  const float* xb = x + (long)b * bstride;
  float acc[4][4];
  #pragma unroll
  for (int r = 0; r < 4; ++r)
    #pragma unroll
    for (int m = 0; m < 4; ++m) acc[r][m] = 0.f;
  int ti = tid >> 4, tj = tid & 15;

  for (int k0 = 0; k0 < C; k0 += 32) {
    int kcnt = min(32, C - k0);
    __syncthreads();
    for (int i = tid; i < kcnt * 64; i += 256) {
      int kc = i >> 6, j = i & 63;
      xs[kc * 65 + j] = xb[(k0 + kc) * NPTS + n0 + j];
    }
    for (int i = tid; i < kcnt * 64; i += 256) {
      int kc = i % kcnt, p = i / kcnt;
      wsd[kc * 65 + p] = Wp[(p0 + p) * C + k0 + kc];
    }
    __syncthreads();
    for (int kc = 0; kc < kcnt; ++kc) {
      float av[4], bv[4];
      #pragma unroll
      for (int r = 0; r < 4; ++r) av[r] = xs[kc * 65 + ti * 4 + r];
      #pragma unroll
      for (int m = 0; m < 4; ++m) bv[m] = wsd[kc * 65 + tj * 4 + m];
      #pragma unroll
      for (int r = 0; r < 4; ++r)
        #pragma unroll
        for (int m = 0; m < 4; ++m) acc[r][m] += av[r] * bv[m];
    }
  }
  #pragma unroll
  for (int r = 0; r < 4; ++r) {
    int n = n0 + ti * 4 + r;
    float4 v = make_float4(acc[r][0], acc[r][1], acc[r][2], acc[r][3]);
    *reinterpret_cast<float4*>(out + (long)(b * NPTS + n) * P2 + p0 + tj * 4) = v;
  }
}

// ---------------- gather + max_k + leaky -> xcat channel block ----------------
__global__ __launch_bounds__(256) void gather_max_kernel(const float* __restrict__ vsus,
                                                         const int* __restrict__ idxin,
                                                         const float* __restrict__ bias,
                                                         float* __restrict__ xcat,
                                                         int O, int cho) {
  __shared__ int idxs[32 * KNN];
  __shared__ float ot[256 * 33];
  int tid = threadIdx.x;
  int b = blockIdx.y;
  int n0 = blockIdx.x * 32;
  int P2 = 2 * O;
  for (int i = tid; i < 32 * KNN; i += 256) idxs[i] = idxin[(b * NPTS + n0) * KNN + i];
  __syncthreads();
  int G = 256 / O;
  int o = tid % O;
  int ns = tid / O;
  float bo = bias[o];
  const float* vb = vsus + (long)b * NPTS * P2;
  for (int step = 0; step < 32 / G; ++step) {
    int nn = step * G + ns;
    float mx = -1e30f;
    for (int k = 0; k < KNN; ++k) {
      int j = idxs[nn * KNN + k];
      mx = fmaxf(mx, vb[j * P2 + o]);
    }
    float us = vb[(n0 + nn) * P2 + O + o] + bo;
    ot[o * 33 + nn] = leaky(mx + us);
  }
  __syncthreads();
  float* ob = xcat + ((long)b * 512 + cho) * NPTS + n0;
  for (int i = tid; i < O * 32; i += 256) {
    int oo = i >> 5, nn = i & 31;
    ob[oo * NPTS + nn] = ot[oo * 33 + nn];
  }
}

// ---------------- mlp: 128x128 tile, 8x8/thread, fused max/sum partials ----------------
__global__ __launch_bounds__(256) void mlp_kernel(const float* __restrict__ xcat,
                                                  const float* __restrict__ Wt,
                                                  const float* __restrict__ bvec,
                                                  float* __restrict__ pbuf) {
  __shared__ float As[32][132];
  __shared__ float Bs[32][132];
  int tid = threadIdx.x;
  int b = blockIdx.z;
  int ob = blockIdx.y;
  int nt = blockIdx.x;
  int o0 = ob * 128, n0 = nt * 128;
  const float* xb = xcat + (long)b * 512 * NPTS;
  int ty = tid >> 4, tx = tid & 15;

  float acc[2][4][2][4];
  #pragma unroll
  for (int q = 0; q < 2; ++q)
    #pragma unroll
    for (int j = 0; j < 4; ++j)
      #pragma unroll
      for (int p = 0; p < 2; ++p)
        #pragma unroll
        for (int i = 0; i < 4; ++i) acc[q][j][p][i] = 0.f;

  for (int k0 = 0; k0 < 512; k0 += 32) {
    __syncthreads();
    #pragma unroll
    for (int s = 0; s < 4; ++s) {
      int f4 = s * 256 + tid;
      int row = f4 >> 5, c4 = f4 & 31;
      *reinterpret_cast<float4*>(&As[row][c4 * 4]) =
          *reinterpret_cast<const float4*>(&Wt[(long)(k0 + row) * 1024 + o0 + c4 * 4]);
      *reinterpret_cast<float4*>(&Bs[row][c4 * 4]) =
          *reinterpret_cast<const float4*>(&xb[(long)(k0 + row) * NPTS + n0 + c4 * 4]);
    }
    __syncthreads();
    #pragma unroll 8
    for (int kc = 0; kc < 32; ++kc) {
      float av[2][4], bv[2][4];
      *reinterpret_cast<float4*>(av[0]) = *reinterpret_cast<const float4*>(&As[kc][ty * 4]);
      *reinterpret_cast<float4*>(av[1]) = *reinterpret_cast<const float4*>(&As[kc][64 + ty * 4]);
      *reinterpret_cast<float4*>(bv[0]) = *reinterpret_cast<const float4*>(&Bs[kc][tx * 4]);
      *reinterpret_cast<float4*>(bv[1]) = *reinterpret_cast<const float4*>(&Bs[kc][64 + tx * 4]);
      #pragma unroll
      for (int q = 0; q < 2; ++q)
        #pragma unroll
        for (int j = 0; j < 4; ++j)
          #pragma unroll
          for (int p = 0; p < 2; ++p)
            #pragma unroll
            for (int i = 0; i < 4; ++i) acc[q][j][p][i] += av[q][j] * bv[p][i];
    }
  }

  float rmax[2][4], rsum[2][4];
  #pragma unroll
  for (int q = 0; q < 2; ++q)
    #pragma unroll
    for (int j = 0; j < 4; ++j) {
      float bb = bvec[o0 + q * 64 + ty * 4 + j];
      float mx = -1e30f, sm = 0.f;
      #pragma unroll
      for (int p = 0; p < 2; ++p)
        #pragma unroll
        for (int i = 0; i < 4; ++i) {
          float y = leaky(acc[q][j][p][i] + bb);
          mx = fmaxf(mx, y);
          sm += y;
        }
      rmax[q][j] = mx;
      rsum[q][j] = sm;
    }
  #pragma unroll
  for (int off = 8; off; off >>= 1) {
    #pragma unroll
    for (int q = 0; q < 2; ++q)
      #pragma unroll
      for (int j = 0; j < 4; ++j) {
        rmax[q][j] = fmaxf(rmax[q][j], __shfl_xor(rmax[q][j], off));
        rsum[q][j] += __shfl_xor(rsum[q][j], off);
      }
  }
  if (tx == 0) {
    float* pb = pbuf + (((long)(b * 8 + ob) * 16 + nt) * 2) * 128;
    #pragma unroll
    for (int q = 0; q < 2; ++q)
      #pragma unroll
      for (int j = 0; j < 4; ++j) {
        int ol = q * 64 + ty * 4 + j;
        pb[ol] = rmax[q][j];
        pb[128 + ol] = rsum[q][j];
      }
  }
}

__global__ void mlp_reduce_kernel(const float* __restrict__ pbuf, float* __restrict__ feat) {
  int t = blockIdx.x * 256 + threadIdx.x;   // 8192
  int b = t >> 10, o = t & 1023;
  int ob = o >> 7, ol = o & 127;
  float mx = -1e30f, s = 0.f;
  for (int nt = 0; nt < 16; ++nt) {
    const float* pb = pbuf + (((long)(b * 8 + ob) * 16 + nt) * 2) * 128;
    mx = fmaxf(mx, pb[ol]);
    s += pb[128 + ol];
  }
  feat[b * 2048 + o] = mx;
  feat[b * 2048 + 1024 + o] = s * (1.f / 2048.f);
}

// ---------------- fc layers: one wave per output ----------------
__global__ void fc_kernel(const float* __restrict__ X, const float* __restrict__ W,
                          const float* __restrict__ bias, const float* __restrict__ g,
                          const float* __restrict__ bb, float* __restrict__ out,
                          int B, int O, int Kdim, int hasAct) {
  int gt = blockIdx.x * 256 + threadIdx.x;
  int wid = gt >> 6;
  int lane = threadIdx.x & 63;
  if (wid >= B * O) return;
  int b = wid / O, o = wid - b * O;
  const float* xr = X + (long)b * Kdim;
  const float* wr = W + (long)o * Kdim;
  float acc = 0.f;
  for (int c = lane; c < Kdim; c += 64) acc += xr[c] * wr[c];
  for (int off = 32; off; off >>= 1) acc += __shfl_down(acc, off);
  if (lane == 0) {
    float h = acc + bias[o];
    if (hasAct) {
      float a = g[o] * rsqrtf(1.0f + 1e-5f);
      h = a * h + bb[o];
      h = fmaxf(h, 0.2f * h);
    }
    out[b * O + o] = h;
  }
}

// ---------------- launch ----------------
extern "C" void kernel_launch(void* const* d_in, const int* in_sizes, int n_in,
                              void* d_out, int out_size, void* d_ws, size_t ws_size,
                              hipStream_t stream) {
  const float* points = (const float*)d_in[0];
  char* ws = (char*)d_ws;

  const size_t XCAT = 0;                         // [8][512][2048] f
  const size_t VSUS = 33554432;                  // [8][2048][512] f (aliased: knn partials, XF, pbuf)
  const size_t IDXB = 67108864;                  // [8][2048][20] i
  const size_t XXB  = 68419584;                  // [8][2048] f
  const size_t WP   = 68485120;                  // [512][128] f
  const size_t WMLP = 68747264;                  // [512][1024] f (k-major)
  const size_t FEAT = 71106560;                  // [8][2048] f
  const size_t H1   = 71172096;                  // [8][512] f
  const size_t H2   = 71188480;                  // [8][256] f

  float* xcat = (float*)(ws + XCAT);
  float* vsus = (float*)(ws + VSUS);
  int*   idxb = (int*)(ws + IDXB);
  float* xxb  = (float*)(ws + XXB);
  float* wp   = (float*)(ws + WP);
  float* wmlp = (float*)(ws + WMLP);
  float* feat = (float*)(ws + FEAT);
  float* h1   = (float*)(ws + H1);
  float* h2   = (float*)(ws + H2);

  // aliased into the vsus region (dead until gemm_vsus / after gather)
  // knnD: 8*4*2048*20*4 = 5.24 MB ; knnI: 2.62 MB ; xfh/xfl: 4 MB each
  float* knnD = (float*)(ws + VSUS);
  unsigned short* knnI = (unsigned short*)(ws + VSUS + 5242880);
  short* xfh = (short*)(ws + VSUS + 8388608);
  short* xfl = (short*)(ws + VSUS + 8388608 + 4194304);
  float* pbuf = (float*)(ws + VSUS);             // 1 MB, used after vsus dead

  struct Layer { const float* x; long bstride; int C, O, cho, wi, gi, bi; };
  Layer layers[4] = {
    { points,              (long)3 * NPTS,   3,   64, 0,   1, 2, 3 },
    { xcat,                (long)512 * NPTS, 64,  64, 64,  4, 5, 6 },
    { xcat + 64 * NPTS,    (long)512 * NPTS, 64,  128, 128, 7, 8, 9 },
    { xcat + 128 * NPTS,   (long)512 * NPTS, 128, 256, 256, 10, 11, 12 },
  };

  for (int L = 0; L < 4; ++L) {
    Layer& ly = layers[L];
    int P2 = 2 * ly.O;
    const float* W = (const float*)d_in[ly.wi];
    const float* g = (const float*)d_in[ly.gi];
    const float* bv = (const float*)d_in[ly.bi];
    int NCHUNK = (ly.C + 31) / 32;

    int wtot = 2 * ly.O * ly.C;
    prep_w_kernel<<<(wtot + 255) / 256, 256, 0, stream>>>(W, g, wp, ly.O, ly.C);
    xx_kernel<<<dim3(NPTS / 256, BATCH), 256, 0, stream>>>(ly.x, xxb, ly.C, ly.bstride);
    split_kernel<<<dim3(NCHUNK * 32, BATCH), 256, 0, stream>>>(
        ly.x, xfh, xfl, ly.C, NCHUNK, ly.bstride);
    dim3 sg(NPTS / 64, KSPLIT, BATCH);
    if (NCHUNK == 1) {
      knn_scan<1><<<sg, 256, 0, stream>>>(xfh, xfl, xxb, knnD, knnI);
    } else if (NCHUNK == 2) {
      knn_scan<2><<<sg, 256, 0, stream>>>(xfh, xfl, xxb, knnD, knnI);
    } else {
      knn_scan<4><<<sg, 256, 0, stream>>>(xfh, xfl, xxb, knnD, knnI);
    }
    knn_merge<<<(BATCH * NPTS) / 256, 256, 0, stream>>>(knnD, knnI, idxb);
    gemm_vsus_kernel<<<dim3(NPTS / 64, P2 / 64, BATCH), 256, 0, stream>>>(
        ly.x, wp, vsus, ly.C, P2, ly.bstride);
    gather_max_kernel<<<dim3(NPTS / 32, BATCH), 256, 0, stream>>>(
        vsus, idxb, bv, xcat, ly.O, ly.cho);
  }

  prep_mlpw_kernel<<<dim3(16, 32), 256, 0, stream>>>(
      (const float*)d_in[13], (const float*)d_in[14], wmlp);
  mlp_kernel<<<dim3(16, 8, BATCH), 256, 0, stream>>>(
      xcat, wmlp, (const float*)d_in[15], pbuf);
  mlp_reduce_kernel<<<32, 256, 0, stream>>>(pbuf, feat);

  fc_kernel<<<(BATCH * 512 * 64) / 256, 256, 0, stream>>>(
      feat, (const float*)d_in[16], (const float*)d_in[17],
      (const float*)d_in[18], (const float*)d_in[19], h1, BATCH, 512, 2048, 1);
  fc_kernel<<<(BATCH * 256 * 64) / 256, 256, 0, stream>>>(
      h1, (const float*)d_in[20], (const float*)d_in[21],
      (const float*)d_in[22], (const float*)d_in[23], h2, BATCH, 256, 512, 1);
  fc_kernel<<<(BATCH * 40 * 64) / 256, 256, 0, stream>>>(
      h2, (const float*)d_in[24], (const float*)d_in[25],
      nullptr, nullptr, (float*)d_out, BATCH, 40, 256, 0);
}

// Round 8
// 963.124 us; speedup vs baseline: 6.6042x; 1.1183x over previous
//
#include <hip/hip_runtime.h>

#define NPTS 2048
#define BATCH 8
#define KNN 20
#define KSPLIT 4

typedef short short8v __attribute__((ext_vector_type(8)));
typedef float f32x4 __attribute__((ext_vector_type(4)));

__device__ __forceinline__ float leaky(float y) { return fmaxf(y, 0.2f * y); }

__device__ __forceinline__ short f2bf(float f) {
  unsigned u = __float_as_uint(f);
  unsigned r = (u + 0x7fffu + ((u >> 16) & 1u)) >> 16;
  return (short)r;
}
__device__ __forceinline__ float bf2f(short h) {
  return __uint_as_float(((unsigned)(unsigned short)h) << 16);
}

// ---------------- prep: Wp[2O][C] = [a*W1 ; a*(W2-W1)] ----------------
__global__ void prep_w_kernel(const float* __restrict__ W, const float* __restrict__ g,
                              float* __restrict__ Wp, int O, int C) {
  int t = blockIdx.x * 256 + threadIdx.x;
  if (t >= 2 * O * C) return;
  int row = t / C, c = t - row * C;
  float inv = rsqrtf(1.0f + 1e-5f);
  if (row < O) {
    Wp[t] = g[row] * inv * W[row * 2 * C + c];
  } else {
    int o = row - O;
    Wp[t] = g[o] * inv * (W[o * 2 * C + C + c] - W[o * 2 * C + c]);
  }
}

// prep mlp weight -> hi/lo bf16 quads, fragment layout, bn scale folded
// Wq[(chunk*4+g)*1024 + o] quad j -> channel c = chunk*32 + g*4 + (j&3) + 16*(j>>2)
__global__ void prep_wq_kernel(const float* __restrict__ W, const float* __restrict__ g,
                               short* __restrict__ wqh, short* __restrict__ wql) {
  int t = blockIdx.x * 256 + threadIdx.x;   // cg*1024 + o, cg < 64
  if (t >= 64 * 1024) return;
  int cg = t >> 10, o = t & 1023;
  int chunk = cg >> 2, gg = cg & 3;
  float scale = g[o] * rsqrtf(1.0f + 1e-5f);
  short8v h8, l8;
  #pragma unroll
  for (int j = 0; j < 8; ++j) {
    int c = chunk * 32 + gg * 4 + (j & 3) + 16 * (j >> 2);
    float v = scale * W[o * 512 + c];
    short h = f2bf(v);
    h8[j] = h;
    l8[j] = f2bf(v - bf2f(h));
  }
  *reinterpret_cast<short8v*>(wqh + (long)t * 8) = h8;
  *reinterpret_cast<short8v*>(wql + (long)t * 8) = l8;
}

// ---------------- xx[b][m] = sum_c x[c][m]^2 (exact fp32) ----------------
__global__ void xx_kernel(const float* __restrict__ x, float* __restrict__ xx,
                          int C, long bstride) {
  int b = blockIdx.y;
  int m = blockIdx.x * 256 + threadIdx.x;
  const float* xb = x + (long)b * bstride;
  float s = 0.f;
  for (int c = 0; c < C; ++c) { float v = xb[c * NPTS + m]; s += v * v; }
  xx[b * NPTS + m] = s;
}

// ---------------- split x into hi/lo bf16 fragment layout (knn) ----------------
__global__ void split_kernel(const float* __restrict__ x, short* __restrict__ xfh,
                             short* __restrict__ xfl, int C, int NCHUNK, long bstride) {
  int b = blockIdx.y;
  int t = blockIdx.x * 256 + threadIdx.x;   // cg*2048 + n
  int cg = t >> 11, n = t & 2047;
  int chunk = cg >> 2, g = cg & 3;
  const float* xb = x + (long)b * bstride;
  short8v h8, l8;
  #pragma unroll
  for (int j = 0; j < 8; ++j) {
    int c = chunk * 32 + g * 4 + (j & 3) + 16 * (j >> 2);
    float v = (c < C) ? xb[c * NPTS + n] : 0.f;
    short h = f2bf(v);
    float lo = v - bf2f(h);
    h8[j] = h;
    l8[j] = f2bf(lo);
  }
  long q = (long)b * NCHUNK * 4 * 2048 + t;
  *reinterpret_cast<short8v*>(xfh + q * 8) = h8;
  *reinterpret_cast<short8v*>(xfl + q * 8) = l8;
}

// ---------------- split xcat (all 512 ch) for mlp ----------------
__global__ void mlp_split_kernel(const float* __restrict__ xcat, short* __restrict__ xqh,
                                 short* __restrict__ xql) {
  int b = blockIdx.y;
  int t = blockIdx.x * 256 + threadIdx.x;   // cg*2048 + n, cg < 64
  int cg = t >> 11, n = t & 2047;
  int chunk = cg >> 2, g = cg & 3;
  const float* xb = xcat + (long)b * 512 * NPTS;
  short8v h8, l8;
  #pragma unroll
  for (int j = 0; j < 8; ++j) {
    int c = chunk * 32 + g * 4 + (j & 3) + 16 * (j >> 2);
    float v = xb[c * NPTS + n];
    short h = f2bf(v);
    h8[j] = h;
    l8[j] = f2bf(v - bf2f(h));
  }
  long q = (long)b * 64 * 2048 + t;
  *reinterpret_cast<short8v*>(xqh + q * 8) = h8;
  *reinterpret_cast<short8v*>(xql + q * 8) = l8;
}

// ---------------- knn scan: MFMA hi/lo d2 gemm + register top-20 + in-wave merge ----------------
template <int NCHUNK>
__global__ __launch_bounds__(256, 5) void knn_scan(const short* __restrict__ xfh,
                                                   const short* __restrict__ xfl,
                                                   const float* __restrict__ xx,
                                                   float* __restrict__ pd,
                                                   unsigned short* __restrict__ pi) {
  __shared__ __align__(16) float smem[6432];
  short8v* qsm = (short8v*)smem;   // single buffer: [8 segs][65 quads]
  float* d2t = smem + 2080;        // [64][68]

  int tid = threadIdx.x;
  int lane = tid & 63, wv = tid >> 6;
  int pt = lane & 15;
  int part = (lane >> 4) & 3;
  int b = blockIdx.z;
  int sidx = blockIdx.y;
  int n0 = blockIdx.x * 64;
  const float* xxb = xx + b * NPTS;
  const short8v* xfh_b = (const short8v*)xfh + (long)b * NCHUNK * 4 * 2048;
  const short8v* xfl_b = (const short8v*)xfl + (long)b * NCHUNK * 4 * 2048;

  short8v afh[NCHUNK], afl[NCHUNK];
  #pragma unroll
  for (int c = 0; c < NCHUNK; ++c) {
    long qi = ((long)(c * 4 + (lane >> 4))) * 2048 + n0 + wv * 16 + pt;
    afh[c] = xfh_b[qi];
    afl[c] = xfl_b[qi];
  }
  float xvr[4];
  #pragma unroll
  for (int r = 0; r < 4; ++r) xvr[r] = xxb[n0 + wv * 16 + (lane >> 4) * 4 + r];

  float ld[20]; int li[20];
  #pragma unroll
  for (int k = 0; k < 20; ++k) { ld[k] = 1e30f; li[k] = 0x7fffffff; }

  int mt0 = sidx * (32 / KSPLIT);

  short8v pA, pB;
  {
    long qi = ((long)(0 * 4 + wv)) * 2048 + mt0 * 64 + lane;
    pA = xfh_b[qi];
    pB = xfl_b[qi];
  }

  for (int mtl = 0; mtl < 32 / KSPLIT; ++mtl) {
    int m0 = (mt0 + mtl) * 64;
    f32x4 acc[4];
    #pragma unroll
    for (int f = 0; f < 4; ++f) acc[f] = (f32x4){0.f, 0.f, 0.f, 0.f};

    #pragma unroll
    for (int c = 0; c < NCHUNK; ++c) {
      __syncthreads();
      qsm[wv * 65 + lane] = pA;
      qsm[(4 + wv) * 65 + lane] = pB;
      __syncthreads();
      int nm = mtl, nc = c + 1;
      if (nc == NCHUNK) { nc = 0; nm = mtl + 1; }
      if (nm < 32 / KSPLIT) {
        long qi = ((long)(nc * 4 + wv)) * 2048 + (mt0 + nm) * 64 + lane;
        pA = xfh_b[qi];
        pB = xfl_b[qi];
      }
      #pragma unroll
      for (int f = 0; f < 4; ++f) {
        short8v bh = qsm[(lane >> 4) * 65 + f * 16 + pt];
        short8v bl = qsm[(4 + (lane >> 4)) * 65 + f * 16 + pt];
        acc[f] = __builtin_amdgcn_mfma_f32_16x16x32_bf16(afh[c], bh, acc[f], 0, 0, 0);
        acc[f] = __builtin_amdgcn_mfma_f32_16x16x32_bf16(afl[c], bh, acc[f], 0, 0, 0);
        acc[f] = __builtin_amdgcn_mfma_f32_16x16x32_bf16(afh[c], bl, acc[f], 0, 0, 0);
        acc[f] = __builtin_amdgcn_mfma_f32_16x16x32_bf16(afl[c], bl, acc[f], 0, 0, 0);
      }
    }

    float xxm[4];
    #pragma unroll
    for (int f = 0; f < 4; ++f) xxm[f] = xxb[m0 + f * 16 + pt];
    #pragma unroll
    for (int f = 0; f < 4; ++f) {
      int col = f * 16 + pt;
      #pragma unroll
      for (int r = 0; r < 4; ++r) {
        int rw = wv * 16 + (lane >> 4) * 4 + r;
        d2t[rw * 68 + col] = xvr[r] + xxm[f] - 2.f * acc[f][r];
      }
    }
    __syncthreads();

    int srow = wv * 16 + pt;
    #pragma unroll
    for (int j4 = 0; j4 < 4; ++j4) {
      f32x4 vq = *reinterpret_cast<f32x4*>(&d2t[srow * 68 + part * 16 + j4 * 4]);
      #pragma unroll
      for (int e = 0; e < 4; ++e) {
        float v = vq[e];
        if (v < ld[19]) {
          int m = m0 + part * 16 + j4 * 4 + e;
          #pragma unroll
          for (int k = 19; k >= 1; --k) {
            bool a = v < ld[k];
            bool s = v < ld[k - 1];
            float nd = a ? (s ? ld[k - 1] : v) : ld[k];
            int   ni = a ? (s ? li[k - 1] : m) : li[k];
            ld[k] = nd; li[k] = ni;
          }
          bool a0 = v < ld[0];
          li[0] = a0 ? m : li[0];
          ld[0] = a0 ? v : ld[0];
        }
      }
    }
  }

  // in-wave 4-way merge: group = lanes {pt, pt+16, pt+32, pt+48}
  long obase = ((long)((b * KSPLIT + sidx) * NPTS) + n0 + wv * 16 + pt) * KNN;
  float h = ld[0]; int hi = li[0];
  #pragma unroll
  for (int k = 0; k < KNN; ++k) {
    float v0 = __shfl(h, pt);        int i0 = __shfl(hi, pt);
    float v1 = __shfl(h, pt + 16);   int i1 = __shfl(hi, pt + 16);
    float v2 = __shfl(h, pt + 32);   int i2 = __shfl(hi, pt + 32);
    float v3 = __shfl(h, pt + 48);   int i3 = __shfl(hi, pt + 48);
    float bv = v0; int bi = i0; int bp = 0;
    if (v1 < bv || (v1 == bv && i1 < bi)) { bv = v1; bi = i1; bp = 1; }
    if (v2 < bv || (v2 == bv && i2 < bi)) { bv = v2; bi = i2; bp = 2; }
    if (v3 < bv || (v3 == bv && i3 < bi)) { bv = v3; bi = i3; bp = 3; }
    if (part == 0) {
      pd[obase + k] = bv;
      pi[obase + k] = (unsigned short)bi;
    }
    bool pop = (part == bp);
    #pragma unroll
    for (int i = 0; i < 19; ++i) {
      ld[i] = pop ? ld[i + 1] : ld[i];
      li[i] = pop ? li[i + 1] : li[i];
    }
    ld[19] = pop ? 1e30f : ld[19];
    li[19] = pop ? 0x7fffffff : li[19];
    h = ld[0]; hi = li[0];
  }
}

// ---------------- knn merge ----------------
__global__ void knn_merge(const float* __restrict__ pd, const unsigned short* __restrict__ pi,
                          int* __restrict__ idxout) {
  int t = blockIdx.x * 256 + threadIdx.x;
  int b = t >> 11, n = t & 2047;
  long base[KSPLIT]; int h[KSPLIT];
  #pragma unroll
  for (int s = 0; s < KSPLIT; ++s) {
    base[s] = ((long)((b * KSPLIT + s) * NPTS) + n) * KNN;
    h[s] = 0;
  }
  int* op = idxout + (long)t * KNN;
  for (int k = 0; k < KNN; ++k) {
    float bv = 1e38f; int bi = 0x7fffffff; int bs = 0;
    #pragma unroll
    for (int s = 0; s < KSPLIT; ++s) {
      float v = pd[base[s] + h[s]];
      int i = pi[base[s] + h[s]];
      if (v < bv || (v == bv && i < bi)) { bv = v; bi = i; bs = s; }
    }
    op[k] = bi;
    #pragma unroll
    for (int s = 0; s < KSPLIT; ++s) h[s] += (bs == s);
  }
}

// ---------------- vsus[b][n][p] = sum_c Wp[p][c] * x[c][n] ----------------
__global__ __launch_bounds__(256) void gemm_vsus_kernel(const float* __restrict__ x,
                                                        const float* __restrict__ Wp,
                                                        float* __restrict__ out,
                                                        int C, int P2, long bstride) {
  __shared__ float xs[32 * 65];
  __shared__ float wsd[32 * 65];
  int tid = threadIdx.x;
  int b = blockIdx.z;
  int n0 = blockIdx.x * 64;
  int p0 = blockIdx.y * 64;
  const float* xb = x + (long)b * bstride;
  float acc[4][4];
  #pragma unroll
  for (int r = 0; r < 4; ++r)
    #pragma unroll
    for (int m = 0; m < 4; ++m) acc[r][m] = 0.f;
  int ti = tid >> 4, tj = tid & 15;

  for (int k0 = 0; k0 < C; k0 += 32) {
    int kcnt = min(32, C - k0);
    __syncthreads();
    for (int i = tid; i < kcnt * 64; i += 256) {
      int kc = i >> 6, j = i & 63;
      xs[kc * 65 + j] = xb[(k0 + kc) * NPTS + n0 + j];
    }
    for (int i = tid; i < kcnt * 64; i += 256) {
      int kc = i % kcnt, p = i / kcnt;
      wsd[kc * 65 + p] = Wp[(p0 + p) * C + k0 + kc];
    }
    __syncthreads();
    for (int kc = 0; kc < kcnt; ++kc) {
      float av[4], bv[4];
      #pragma unroll
      for (int r = 0; r < 4; ++r) av[r] = xs[kc * 65 + ti * 4 + r];
      #pragma unroll
      for (int m = 0; m < 4; ++m) bv[m] = wsd[kc * 65 + tj * 4 + m];
      #pragma unroll
      for (int r = 0; r < 4; ++r)
        #pragma unroll
        for (int m = 0; m < 4; ++m) acc[r][m] += av[r] * bv[m];
    }
  }
  #pragma unroll
  for (int r = 0; r < 4; ++r) {
    int n = n0 + ti * 4 + r;
    float4 v = make_float4(acc[r][0], acc[r][1], acc[r][2], acc[r][3]);
    *reinterpret_cast<float4*>(out + (long)(b * NPTS + n) * P2 + p0 + tj * 4) = v;
  }
}

// ---------------- gather + max_k + leaky -> xcat channel block ----------------
__global__ __launch_bounds__(256) void gather_max_kernel(const float* __restrict__ vsus,
                                                         const int* __restrict__ idxin,
                                                         const float* __restrict__ bias,
                                                         float* __restrict__ xcat,
                                                         int O, int cho) {
  __shared__ int idxs[32 * KNN];
  __shared__ float ot[256 * 33];
  int tid = threadIdx.x;
  int b = blockIdx.y;
  int n0 = blockIdx.x * 32;
  int P2 = 2 * O;
  for (int i = tid; i < 32 * KNN; i += 256) idxs[i] = idxin[(b * NPTS + n0) * KNN + i];
  __syncthreads();
  int G = 256 / O;
  int o = tid % O;
  int ns = tid / O;
  float bo = bias[o];
  const float* vb = vsus + (long)b * NPTS * P2;
  for (int step = 0; step < 32 / G; ++step) {
    int nn = step * G + ns;
    float mx = -1e30f;
    for (int k = 0; k < KNN; ++k) {
      int j = idxs[nn * KNN + k];
      mx = fmaxf(mx, vb[j * P2 + o]);
    }
    float us = vb[(n0 + nn) * P2 + O + o] + bo;
    ot[o * 33 + nn] = leaky(mx + us);
  }
  __syncthreads();
  float* ob = xcat + ((long)b * 512 + cho) * NPTS + n0;
  for (int i = tid; i < O * 32; i += 256) {
    int oo = i >> 5, nn = i & 31;
    ob[oo * NPTS + nn] = ot[oo * 33 + nn];
  }
}

// ---------------- mlp: MFMA hi/lo (3 products), 128x128 block, fused max/sum ----------------
__global__ __launch_bounds__(256) void mlp_kernel(const short* __restrict__ xqh,
                                                  const short* __restrict__ xql,
                                                  const short* __restrict__ wqh,
                                                  const short* __restrict__ wql,
                                                  const float* __restrict__ bvec,
                                                  float* __restrict__ pbuf) {
  __shared__ __align__(16) short8v qsmX[2 * 4 * 130];   // [hl][g][130] quads
  __shared__ float redM[4][64];
  __shared__ float redS[4][64];
  int tid = threadIdx.x;
  int lane = tid & 63, wv = tid >> 6;
  int pt = lane & 15, kg = lane >> 4;
  int b = blockIdx.z, ob = blockIdx.y, nt = blockIdx.x;
  int o0 = ob * 128, n0 = nt * 128;
  int ow = o0 + (wv >> 1) * 64;
  int nwoff = (wv & 1) * 64;
  const short8v* xqh_b = (const short8v*)xqh + (long)b * 64 * 2048;
  const short8v* xql_b = (const short8v*)xql + (long)b * 64 * 2048;
  const short8v* wqh_q = (const short8v*)wqh;
  const short8v* wql_q = (const short8v*)wql;

  f32x4 acc[4][4];
  #pragma unroll
  for (int f2 = 0; f2 < 4; ++f2)
    #pragma unroll
    for (int fb = 0; fb < 4; ++fb) acc[f2][fb] = (f32x4){0.f, 0.f, 0.f, 0.f};

  for (int chunk = 0; chunk < 16; ++chunk) {
    __syncthreads();
    #pragma unroll
    for (int s = 0; s < 4; ++s) {
      int idx = s * 256 + tid;        // 0..1023
      int hl = idx >> 9, rem = idx & 511, g = rem >> 7, n = rem & 127;
      const short8v* src = hl ? xql_b : xqh_b;
      qsmX[hl * 520 + g * 130 + n] = src[(long)(chunk * 4 + g) * 2048 + n0 + n];
    }
    __syncthreads();
    short8v ah[4], al[4];
    #pragma unroll
    for (int f2 = 0; f2 < 4; ++f2) {
      long qi = (long)(chunk * 4 + kg) * 1024 + ow + f2 * 16 + pt;
      ah[f2] = wqh_q[qi];
      al[f2] = wql_q[qi];
    }
    #pragma unroll
    for (int fb = 0; fb < 4; ++fb) {
      short8v bh = qsmX[0 * 520 + kg * 130 + nwoff + fb * 16 + pt];
      short8v bl = qsmX[1 * 520 + kg * 130 + nwoff + fb * 16 + pt];
      #pragma unroll
      for (int f2 = 0; f2 < 4; ++f2) {
        acc[f2][fb] = __builtin_amdgcn_mfma_f32_16x16x32_bf16(ah[f2], bh, acc[f2][fb], 0, 0, 0);
        acc[f2][fb] = __builtin_amdgcn_mfma_f32_16x16x32_bf16(al[f2], bh, acc[f2][fb], 0, 0, 0);
        acc[f2][fb] = __builtin_amdgcn_mfma_f32_16x16x32_bf16(ah[f2], bl, acc[f2][fb], 0, 0, 0);
      }
    }
  }

  // epilogue: o = ow + f2*16 + kg*4 + r ; n = n0 + nwoff + fb*16 + pt
  #pragma unroll
  for (int f2 = 0; f2 < 4; ++f2) {
    #pragma unroll
    for (int r = 0; r < 4; ++r) {
      float bb = bvec[ow + f2 * 16 + kg * 4 + r];
      float mx = -1e30f, sm = 0.f;
      #pragma unroll
      for (int fb = 0; fb < 4; ++fb) {
        float y = leaky(acc[f2][fb][r] + bb);
        mx = fmaxf(mx, y);
        sm += y;
      }
      #pragma unroll
      for (int off = 1; off < 16; off <<= 1) {
        mx = fmaxf(mx, __shfl_xor(mx, off));
        sm += __shfl_xor(sm, off);
      }
      if (pt == 0) {
        redM[wv][f2 * 16 + kg * 4 + r] = mx;
        redS[wv][f2 * 16 + kg * 4 + r] = sm;
      }
    }
  }
  __syncthreads();
  if (tid < 128) {
    int os = tid >> 6, ol = tid & 63;
    float mx = fmaxf(redM[os * 2 + 0][ol], redM[os * 2 + 1][ol]);
    float sm = redS[os * 2 + 0][ol] + redS[os * 2 + 1][ol];
    float* pb = pbuf + (((long)(b * 8 + ob) * 16 + nt) * 2) * 128;
    pb[os * 64 + ol] = mx;
    pb[128 + os * 64 + ol] = sm;
  }
}

__global__ void mlp_reduce_kernel(const float* __restrict__ pbuf, float* __restrict__ feat) {
  int t = blockIdx.x * 256 + threadIdx.x;   // 8192
  int b = t >> 10, o = t & 1023;
  int ob = o >> 7, ol = o & 127;
  float mx = -1e30f, s = 0.f;
  for (int nt = 0; nt < 16; ++nt) {
    const float* pb = pbuf + (((long)(b * 8 + ob) * 16 + nt) * 2) * 128;
    mx = fmaxf(mx, pb[ol]);
    s += pb[128 + ol];
  }
  feat[b * 2048 + o] = mx;
  feat[b * 2048 + 1024 + o] = s * (1.f / 2048.f);
}

// ---------------- fc layers: one wave per output ----------------
__global__ void fc_kernel(const float* __restrict__ X, const float* __restrict__ W,
                          const float* __restrict__ bias, const float* __restrict__ g,
                          const float* __restrict__ bb, float* __restrict__ out,
                          int B, int O, int Kdim, int hasAct) {
  int gt = blockIdx.x * 256 + threadIdx.x;
  int wid = gt >> 6;
  int lane = threadIdx.x & 63;
  if (wid >= B * O) return;
  int b = wid / O, o = wid - b * O;
  const float* xr = X + (long)b * Kdim;
  const float* wr = W + (long)o * Kdim;
  float acc = 0.f;
  for (int c = lane; c < Kdim; c += 64) acc += xr[c] * wr[c];
  for (int off = 32; off; off >>= 1) acc += __shfl_down(acc, off);
  if (lane == 0) {
    float h = acc + bias[o];
    if (hasAct) {
      float a = g[o] * rsqrtf(1.0f + 1e-5f);
      h = a * h + bb[o];
      h = fmaxf(h, 0.2f * h);
    }
    out[b * O + o] = h;
  }
}

// ---------------- launch ----------------
extern "C" void kernel_launch(void* const* d_in, const int* in_sizes, int n_in,
                              void* d_out, int out_size, void* d_ws, size_t ws_size,
                              hipStream_t stream) {
  const float* points = (const float*)d_in[0];
  char* ws = (char*)d_ws;

  const size_t XCAT = 0;                         // [8][512][2048] f
  const size_t VSUS = 33554432;                  // 33.5 MB aliased region
  const size_t IDXB = 67108864;                  // [8][2048][20] i (also mlp pbuf)
  const size_t XXB  = 68419584;                  // [8][2048] f
  const size_t WP   = 68485120;                  // [512][128] f
  const size_t WMLP = 68747264;                  // mlp weight quads hi/lo (2 MB)
  const size_t FEAT = 71106560;                  // [8][2048] f
  const size_t H1   = 71172096;                  // [8][512] f
  const size_t H2   = 71188480;                  // [8][256] f

  float* xcat = (float*)(ws + XCAT);
  float* vsus = (float*)(ws + VSUS);
  int*   idxb = (int*)(ws + IDXB);
  float* xxb  = (float*)(ws + XXB);
  float* wp   = (float*)(ws + WP);
  float* feat = (float*)(ws + FEAT);
  float* h1   = (float*)(ws + H1);
  float* h2   = (float*)(ws + H2);

  // aliased into the vsus region (stream-ordered reuse)
  float* knnD = (float*)(ws + VSUS);
  unsigned short* knnI = (unsigned short*)(ws + VSUS + 5242880);
  short* xfh = (short*)(ws + VSUS + 8388608);
  short* xfl = (short*)(ws + VSUS + 8388608 + 4194304);
  // mlp X quads fill the whole vsus region after layer-4 gather
  short* xqh = (short*)(ws + VSUS);
  short* xql = (short*)(ws + VSUS + 16777216);
  // mlp pbuf aliases dead idxb (1 MB <= 1.31 MB)
  float* pbuf = (float*)(ws + IDXB);
  short* wqh = (short*)(ws + WMLP);
  short* wql = (short*)(ws + WMLP + 1048576);

  struct Layer { const float* x; long bstride; int C, O, cho, wi, gi, bi; };
  Layer layers[4] = {
    { points,              (long)3 * NPTS,   3,   64, 0,   1, 2, 3 },
    { xcat,                (long)512 * NPTS, 64,  64, 64,  4, 5, 6 },
    { xcat + 64 * NPTS,    (long)512 * NPTS, 64,  128, 128, 7, 8, 9 },
    { xcat + 128 * NPTS,   (long)512 * NPTS, 128, 256, 256, 10, 11, 12 },
  };

  for (int L = 0; L < 4; ++L) {
    Layer& ly = layers[L];
    int P2 = 2 * ly.O;
    const float* W = (const float*)d_in[ly.wi];
    const float* g = (const float*)d_in[ly.gi];
    const float* bv = (const float*)d_in[ly.bi];
    int NCHUNK = (ly.C + 31) / 32;

    int wtot = 2 * ly.O * ly.C;
    prep_w_kernel<<<(wtot + 255) / 256, 256, 0, stream>>>(W, g, wp, ly.O, ly.C);
    xx_kernel<<<dim3(NPTS / 256, BATCH), 256, 0, stream>>>(ly.x, xxb, ly.C, ly.bstride);
    split_kernel<<<dim3(NCHUNK * 32, BATCH), 256, 0, stream>>>(
        ly.x, xfh, xfl, ly.C, NCHUNK, ly.bstride);
    dim3 sg(NPTS / 64, KSPLIT, BATCH);
    if (NCHUNK == 1) {
      knn_scan<1><<<sg, 256, 0, stream>>>(xfh, xfl, xxb, knnD, knnI);
    } else if (NCHUNK == 2) {
      knn_scan<2><<<sg, 256, 0, stream>>>(xfh, xfl, xxb, knnD, knnI);
    } else {
      knn_scan<4><<<sg, 256, 0, stream>>>(xfh, xfl, xxb, knnD, knnI);
    }
    knn_merge<<<(BATCH * NPTS) / 256, 256, 0, stream>>>(knnD, knnI, idxb);
    gemm_vsus_kernel<<<dim3(NPTS / 64, P2 / 64, BATCH), 256, 0, stream>>>(
        ly.x, wp, vsus, ly.C, P2, ly.bstride);
    gather_max_kernel<<<dim3(NPTS / 32, BATCH), 256, 0, stream>>>(
        vsus, idxb, bv, xcat, ly.O, ly.cho);
  }

  prep_wq_kernel<<<256, 256, 0, stream>>>(
      (const float*)d_in[13], (const float*)d_in[14], wqh, wql);
  mlp_split_kernel<<<dim3(512, BATCH), 256, 0, stream>>>(xcat, xqh, xql);
  mlp_kernel<<<dim3(16, 8, BATCH), 256, 0, stream>>>(
      xqh, xql, wqh, wql, (const float*)d_in[15], pbuf);
  mlp_reduce_kernel<<<32, 256, 0, stream>>>(pbuf, feat);

  fc_kernel<<<(BATCH * 512 * 64) / 256, 256, 0, stream>>>(
      feat, (const float*)d_in[16], (const float*)d_in[17],
      (const float*)d_in[18], (const float*)d_in[19], h1, BATCH, 512, 2048, 1);
  fc_kernel<<<(BATCH * 256 * 64) / 256, 256, 0, stream>>>(
      h1, (const float*)d_in[20], (const float*)d_in[21],
      (const float*)d_in[22], (const float*)d_in[23], h2, BATCH, 256, 512, 1);
  fc_kernel<<<(BATCH * 40 * 64) / 256, 256, 0, stream>>>(
      h2, (const float*)d_in[24], (const float*)d_in[25],
      nullptr, nullptr, (float*)d_out, BATCH, 40, 256, 0);
}